// Round 5
// baseline (412.484 us; speedup 1.0000x reference)
//
#include <hip/hip_runtime.h>
#include <cstdint>

typedef __bf16 bf16_t;
typedef __bf16 bf16x4 __attribute__((ext_vector_type(4)));
typedef __bf16 bf16x8 __attribute__((ext_vector_type(8)));
typedef float f32x4 __attribute__((ext_vector_type(4)));

#define B_ 4
#define S_ 1024
#define D_ 1024
#define HID_ 4096
#define MEG (1u << 20)

// ---------------- workspace layout (bytes) ----------------
static const size_t OFF_WBF  = 0;                 // 12M bf16 (Wq,Wk,Wv,Wo,W1,W2)
static const size_t OFF_BQKV = 25165824;          // 3072 f32
static const size_t OFF_MOD  = 25178112;          // 4*6144 f32
static const size_t OFF_H    = 25276416;          // 4096*1024 bf16
static const size_t OFF_QKV  = 33665024;          // 4096*3072 bf16
static const size_t OFF_VT   = 58830848;          // 4*16*64*1024 bf16
static const size_t OFF_ATTN = 67219456;          // 4096*1024 bf16
static const size_t OFF_X1   = 75608064;          // 4096*1024 f32
static const size_t OFF_PART = 92385280;          // 2 * 4096*1024 f32 (split-K partials)
static const size_t OFF_MLPH = 159494144;         // 4096*4096 bf16 = 32MB

// ---------------- async global->LDS (16B/lane) ----------------
__device__ __forceinline__ void async_copy16(const bf16_t* g, bf16_t* l) {
  __builtin_amdgcn_global_load_lds(
      (__attribute__((address_space(1))) void*)(g),
      (__attribute__((address_space(3))) void*)(l), 16, 0, 0);
}

// ---------------- weight convert + bias pack ----------------
__global__ __launch_bounds__(256) void convert_pack(
    const float* __restrict__ Wq, const float* __restrict__ Wk,
    const float* __restrict__ Wv, const float* __restrict__ Wo,
    const float* __restrict__ W1, const float* __restrict__ W2,
    const float* __restrict__ bq, const float* __restrict__ bk,
    const float* __restrict__ bv, bf16_t* __restrict__ wbf,
    float* __restrict__ bqkv) {
  const int y = blockIdx.y;
  if (y == 6) {
    int i = blockIdx.x * 256 + threadIdx.x;
    if (i < 3072)
      bqkv[i] = i < 1024 ? bq[i] : (i < 2048 ? bk[i - 1024] : bv[i - 2048]);
    return;
  }
  const float* src; bf16_t* dst; int n;
  switch (y) {
    case 0: src = Wq; dst = wbf;           n = MEG;     break;
    case 1: src = Wk; dst = wbf + MEG;     n = MEG;     break;
    case 2: src = Wv; dst = wbf + 2*MEG;   n = MEG;     break;
    case 3: src = Wo; dst = wbf + 3*MEG;   n = MEG;     break;
    case 4: src = W1; dst = wbf + 4*MEG;   n = 4*MEG;   break;
    default: src = W2; dst = wbf + 8*MEG;  n = 4*MEG;   break;
  }
  int idx = (blockIdx.x * 256 + threadIdx.x) * 4;
  if (idx < n) {
    float4 v = *(const float4*)(src + idx);
    bf16x4 pk;
    pk.x = (__bf16)v.x; pk.y = (__bf16)v.y; pk.z = (__bf16)v.z; pk.w = (__bf16)v.w;
    *(bf16x4*)(dst + idx) = pk;
  }
}

// ---------------- adaLN: one wave per output o, all 4 batches ----------------
__global__ __launch_bounds__(256) void ada_mod(
    const float* __restrict__ cond, const float* __restrict__ Wada,
    const float* __restrict__ bada, float* __restrict__ mod) {
  const int wave = threadIdx.x >> 6, lane = threadIdx.x & 63;
  const int o = blockIdx.x * 4 + wave;      // 0..6143
  const float* wr = Wada + (size_t)o * D_;
  float a0 = 0.f, a1 = 0.f, a2 = 0.f, a3 = 0.f;
#pragma unroll
  for (int l = 0; l < 16; l++) {
    int i = l * 64 + lane;
    float w = wr[i];
    float c0 = cond[i], c1 = cond[1024 + i], c2 = cond[2048 + i], c3 = cond[3072 + i];
    a0 += w * (c0 / (1.0f + __expf(-c0)));
    a1 += w * (c1 / (1.0f + __expf(-c1)));
    a2 += w * (c2 / (1.0f + __expf(-c2)));
    a3 += w * (c3 / (1.0f + __expf(-c3)));
  }
#pragma unroll
  for (int offs = 32; offs; offs >>= 1) {
    a0 += __shfl_xor(a0, offs);
    a1 += __shfl_xor(a1, offs);
    a2 += __shfl_xor(a2, offs);
    a3 += __shfl_xor(a3, offs);
  }
  if (lane == 0) {
    float bb = bada[o];
    mod[o]          = a0 + bb;
    mod[6144 + o]   = a1 + bb;
    mod[12288 + o]  = a2 + bb;
    mod[18432 + o]  = a3 + bb;
  }
}

// ---------------- LayerNorm + modulate -> bf16 ----------------
__global__ __launch_bounds__(256) void ln_modulate(
    const float* __restrict__ X, const float* __restrict__ mod,
    bf16_t* __restrict__ H, int goff) {
  const int row = blockIdx.x;
  const int b = row >> 10;
  const int t = threadIdx.x;
  const float* xr = X + (size_t)row * D_;
  float4 xv = *(const float4*)(xr + t * 4);
  float s = xv.x + xv.y + xv.z + xv.w;
  float q = xv.x*xv.x + xv.y*xv.y + xv.z*xv.z + xv.w*xv.w;
  const int wave = t >> 6, lane = t & 63;
#pragma unroll
  for (int offs = 32; offs; offs >>= 1) {
    s += __shfl_down(s, offs);
    q += __shfl_down(q, offs);
  }
  __shared__ float sb[4][2];
  if (lane == 0) { sb[wave][0] = s; sb[wave][1] = q; }
  __syncthreads();
  float st = sb[0][0] + sb[1][0] + sb[2][0] + sb[3][0];
  float qt = sb[0][1] + sb[1][1] + sb[2][1] + sb[3][1];
  float mu = st * (1.0f / D_);
  float var = qt * (1.0f / D_) - mu * mu;
  float rstd = rsqrtf(var + 1e-6f);
  const float* mb = mod + (size_t)b * 6144 + goff;
  const int c = t * 4;
  float4 gm = *(const float4*)(mb + c);
  float4 bt = *(const float4*)(mb + 1024 + c);
  bf16x4 pk;
  pk.x = (__bf16)((xv.x - mu) * rstd * (1.0f + bt.x) + gm.x);
  pk.y = (__bf16)((xv.y - mu) * rstd * (1.0f + bt.y) + gm.y);
  pk.z = (__bf16)((xv.z - mu) * rstd * (1.0f + bt.z) + gm.z);
  pk.w = (__bf16)((xv.w - mu) * rstd * (1.0f + bt.w) + gm.w);
  *(bf16x4*)(H + (size_t)row * D_ + c) = pk;
}

// ---------------- V transpose: vT[b,h,d,s] <- qkv[b,s, 2048+h*64+d] ----------------
__global__ __launch_bounds__(256) void transpose_v(
    const bf16_t* __restrict__ qkv, bf16_t* __restrict__ vT) {
  __shared__ bf16_t tile[64][65];
  const int bh = blockIdx.y;
  const int b = bh >> 4, hh = bh & 15;
  const int s0 = blockIdx.x * 64;
  const int t = threadIdx.x;
  const int tx = t & 63, ty = t >> 6;
  const bf16_t* src = qkv + (size_t)b * S_ * 3072 + 2048 + hh * 64;
  for (int r = ty; r < 64; r += 4)
    tile[r][tx] = src[(size_t)(s0 + r) * 3072 + tx];
  __syncthreads();
  bf16_t* dst = vT + (size_t)bh * 64 * 1024;
  for (int r = ty; r < 64; r += 4)
    dst[(size_t)r * 1024 + s0 + tx] = tile[tx][r];
}

// ---------------- flash attention (v4) ----------------
// QBLK=128, 512 threads (8 waves); K/V LDS shared; KBLK=128 softmax
// granularity; dbuf prefetch before compute; deferred cross-lane sum.
// LDS = 80KB -> 2 blocks/CU = 16 waves/CU.
__global__ __launch_bounds__(512, 4) void flash_attn(
    const bf16_t* __restrict__ qkv, const bf16_t* __restrict__ vT,
    bf16_t* __restrict__ attn) {
  __shared__ __align__(16) bf16_t Ks[2][2][64 * 64];
  __shared__ __align__(16) bf16_t Vs[2][2][64 * 64];
  __shared__ __align__(16) bf16_t Ps[8][16 * 64];

  const int t = threadIdx.x;
  const int wave = t >> 6, lane = t & 63;
  const int lm = lane & 15, quad = lane >> 4;
  const int bh = blockIdx.y;
  const int b = bh >> 4, hh = bh & 15;
  const int s0 = blockIdx.x * 128;

  const bf16_t* qbase = qkv + (size_t)b * S_ * 3072 + hh * 64;
  const bf16_t* kbase = qbase + 1024;
  const bf16_t* vbase = vT + (size_t)bh * (64 * 1024);

  const int row0 = t >> 3;            // 0..63
  const int cg = (t & 7) ^ (row0 & 7);
  const int od = t * 8;               // LDS element offset

  async_copy16(qbase + (size_t)(s0 + row0) * 3072 + cg * 8, &Ks[1][0][od]);
  async_copy16(qbase + (size_t)(s0 + 64 + row0) * 3072 + cg * 8, &Ks[1][1][od]);
  async_copy16(kbase + (size_t)row0 * 3072 + cg * 8, &Ks[0][0][od]);
  async_copy16(kbase + (size_t)(64 + row0) * 3072 + cg * 8, &Ks[0][1][od]);
  async_copy16(vbase + (size_t)row0 * 1024 + cg * 8, &Vs[0][0][od]);
  async_copy16(vbase + (size_t)row0 * 1024 + 64 + cg * 8, &Vs[0][1][od]);
  __syncthreads();

  bf16x8 aq0, aq1;
  {
    const int rq = wave * 16 + lm;
    const int qh = rq >> 6, qr = rq & 63;
    const int rbq = lm & 7;
    aq0 = *(const bf16x8*)&Ks[1][qh][qr * 64 + (quad ^ rbq) * 8];
    aq1 = *(const bf16x8*)&Ks[1][qh][qr * 64 + ((4 + quad) ^ rbq) * 8];
  }
  __syncthreads();

  f32x4 accO[4] = {};
  float mrow[4], lsum[4];
#pragma unroll
  for (int r = 0; r < 4; r++) { mrow[r] = -1e30f; lsum[r] = 0.f; }

  const float SC = 0.18033688f;         // 0.125 * log2(e): exp2 domain
  const int rb = lm & 7;
  bf16_t* Pw = Ps[wave];

  for (int tt = 0; tt < 8; ++tt) {
    const int cur = tt & 1;
    if (tt < 7) {
      const int nb = cur ^ 1;
      const size_t k0n = (size_t)(tt + 1) << 7;
      async_copy16(kbase + (k0n + row0) * 3072 + cg * 8, &Ks[nb][0][od]);
      async_copy16(kbase + (k0n + 64 + row0) * 3072 + cg * 8, &Ks[nb][1][od]);
      async_copy16(vbase + (size_t)row0 * 1024 + k0n + cg * 8, &Vs[nb][0][od]);
      async_copy16(vbase + (size_t)row0 * 1024 + k0n + 64 + cg * 8, &Vs[nb][1][od]);
    }

    f32x4 accS[8];
#pragma unroll
    for (int j = 0; j < 8; j++) accS[j] = (f32x4){0.f, 0.f, 0.f, 0.f};
    __builtin_amdgcn_s_setprio(1);
#pragma unroll
    for (int hf = 0; hf < 2; hf++) {
#pragma unroll
      for (int ni = 0; ni < 4; ni++) {
        const int rk = ni * 16 + lm;
        bf16x8 b0 = *(const bf16x8*)&Ks[cur][hf][rk * 64 + ((quad ^ rb)) * 8];
        bf16x8 b1 = *(const bf16x8*)&Ks[cur][hf][rk * 64 + (((4 + quad) ^ rb)) * 8];
        f32x4 a = accS[hf * 4 + ni];
        a = __builtin_amdgcn_mfma_f32_16x16x32_bf16(aq0, b0, a, 0, 0, 0);
        a = __builtin_amdgcn_mfma_f32_16x16x32_bf16(aq1, b1, a, 0, 0, 0);
        accS[hf * 4 + ni] = a;
      }
    }
    __builtin_amdgcn_s_setprio(0);

    float mx[4];
#pragma unroll
    for (int r = 0; r < 4; r++) {
      float m0 = fmaxf(fmaxf(accS[0][r], accS[1][r]), fmaxf(accS[2][r], accS[3][r]));
      float m1 = fmaxf(fmaxf(accS[4][r], accS[5][r]), fmaxf(accS[6][r], accS[7][r]));
      float m8 = fmaxf(m0, m1);
      m8 = fmaxf(m8, __shfl_xor(m8, 1));
      m8 = fmaxf(m8, __shfl_xor(m8, 2));
      m8 = fmaxf(m8, __shfl_xor(m8, 4));
      m8 = fmaxf(m8, __shfl_xor(m8, 8));
      mx[r] = m8 * SC;
    }
    bool ok = (mx[0] - mrow[0] <= 8.0f) && (mx[1] - mrow[1] <= 8.0f) &&
              (mx[2] - mrow[2] <= 8.0f) && (mx[3] - mrow[3] <= 8.0f);
    if (!__all(ok)) {
#pragma unroll
      for (int r = 0; r < 4; r++) {
        float mnew = fmaxf(mrow[r], mx[r]);
        float al = exp2f(mrow[r] - mnew);
        mrow[r] = mnew;
        lsum[r] *= al;
#pragma unroll
        for (int di = 0; di < 4; di++) accO[di][r] *= al;
      }
    }
#pragma unroll
    for (int r = 0; r < 4; r++) {
      float sum = 0.f;
#pragma unroll
      for (int j = 0; j < 8; j++) {
        float p = exp2f(accS[j][r] * SC - mrow[r]);
        accS[j][r] = p;
        sum += p;
      }
      lsum[r] += sum;
    }

#pragma unroll
    for (int hf = 0; hf < 2; hf++) {
#pragma unroll
      for (int jj = 0; jj < 4; jj++)
#pragma unroll
        for (int r = 0; r < 4; r++) {
          int prow = quad * 4 + r;
          int c = jj * 16 + lm;
          Pw[prow * 64 + (((c >> 3) ^ (prow & 7)) << 3) + (c & 7)] =
              (__bf16)accS[hf * 4 + jj][r];
        }
      __builtin_amdgcn_s_setprio(1);
#pragma unroll
      for (int loc = 0; loc < 2; loc++) {
        bf16x8 ap = *(const bf16x8*)&Pw[lm * 64 + (((loc * 4 + quad) ^ rb)) * 8];
#pragma unroll
        for (int di = 0; di < 4; di++) {
          const int rv = di * 16 + lm;
          bf16x8 vv = *(const bf16x8*)&Vs[cur][hf]
              [rv * 64 + (((loc * 4 + quad) ^ rb)) * 8];
          accO[di] = __builtin_amdgcn_mfma_f32_16x16x32_bf16(ap, vv, accO[di], 0, 0, 0);
        }
      }
      __builtin_amdgcn_s_setprio(0);
    }
    __syncthreads();
  }

#pragma unroll
  for (int r = 0; r < 4; r++) {
    float sv = lsum[r];
    sv += __shfl_xor(sv, 1);
    sv += __shfl_xor(sv, 2);
    sv += __shfl_xor(sv, 4);
    sv += __shfl_xor(sv, 8);
    lsum[r] = sv;
  }

#pragma unroll
  for (int r = 0; r < 4; r++) {
    float inv = 1.0f / lsum[r];
    int prow = quad * 4 + r;
#pragma unroll
    for (int di = 0; di < 4; di++) {
      int col = di * 16 + lm;
      int cph = (col >> 3) ^ (prow & 7);
      Pw[prow * 64 + cph * 8 + (col & 7)] = (__bf16)(accO[di][r] * inv);
    }
  }
  bf16_t* abase = attn + (size_t)b * S_ * 1024 +
                  (size_t)(s0 + wave * 16) * 1024 + hh * 64;
#pragma unroll
  for (int it = 0; it < 2; it++) {
    int slot = it * 64 + lane;
    int orow = slot >> 3;
    int gc = slot & 7;
    int cph = gc ^ (orow & 7);
    bf16x8 val = *(const bf16x8*)&Pw[orow * 64 + cph * 8];
    *(bf16x8*)(abase + (size_t)orow * 1024 + gc * 8) = val;
  }
}

// ---------------- C = A * B^T GEMM v6: 512 threads, BM=256 BN=128 BK=64 ------
// 8 waves (4 M x 2 N), per-wave 64x64 output (acc[4][4]). Ring-of-3 LDS
// (144KB), staged 2 K-tiles ahead, counted s_waitcnt vmcnt(6) (never 0 in
// the main loop). One barrier per 32-MFMA iteration. 64-col XOR swizzle
// identical to flash_attn's proven zero-conflict tiles:
//   LDS slot s of row r holds global chunk s ^ (r&7); reader slot =
//   (ks*4+quad) ^ (lm&7).
// XCD-aware bijective swizzle (grid blocks must be multiple of 8).
// M mult of 256; N mult of 128; K mult of 64; K/64 >= 3.
// EPI: 0 = (+bias) -> bf16 ; 1 = identity -> f32 ; 3 = gelu(acc+bias) -> bf16
template <int EPI>
__global__ __launch_bounds__(512) void gemm_bt(
    const bf16_t* __restrict__ A, int lda, long long sAz,
    const bf16_t* __restrict__ B, int ldb, long long sBz,
    void* __restrict__ Cv, int ldc, long long sCz,
    int M, int N, int K,
    const float* __restrict__ bias,
    float scale) {
  __shared__ __align__(16) bf16_t As[3][256 * 64];   // 96KB
  __shared__ __align__(16) bf16_t Bs[3][128 * 64];   // 48KB

  const int z = blockIdx.z;
  A += (size_t)z * sAz;
  B += (size_t)z * sBz;

  // bijective XCD swizzle: nwg % 8 == 0 guaranteed by launch geometry
  const int gx = gridDim.x;
  int d = blockIdx.x + gx * blockIdx.y;
  {
    const int cpx = (gx * gridDim.y) >> 3;
    int wg = (d & 7) * cpx + (d >> 3);
    const int by = wg / gx;     // M-tile
    const int bx = wg % gx;     // N-tile

    const int t = threadIdx.x;
    const int wave = t >> 6;
    const int lane = t & 63;
    const int lm = lane & 15;
    const int quad = lane >> 4;
    const int wr = wave >> 1;   // 0..3: M sub-block
    const int wc = wave & 1;    // 0..1: N sub-block

    const int m0 = by * 256;
    const int n0 = bx * 128;

    f32x4 acc[4][4] = {};

    // staging: one gload unit = 64 rows x 64 cols (8KB); thread t -> row t>>3,
    // LDS slot t&7 holds global chunk (t&7)^(row&7)
    const int srow = t >> 3;                    // 0..63
    const int scg = (t & 7) ^ (srow & 7);
    const int sod = t * 8;                      // LDS elem offset in unit
    const bf16_t* Ag = A + (size_t)(m0 + srow) * lda + scg * 8;
    const bf16_t* Bg = B + (size_t)(n0 + srow) * ldb + scg * 8;
    const size_t a64 = (size_t)64 * lda, a128 = (size_t)128 * lda,
                 a192 = (size_t)192 * lda, b64 = (size_t)64 * ldb;

#define STAGE6(buf, ko)                                      \
  async_copy16(Ag + (ko), &As[buf][sod]);                    \
  async_copy16(Ag + a64 + (ko), &As[buf][4096 + sod]);       \
  async_copy16(Ag + a128 + (ko), &As[buf][8192 + sod]);      \
  async_copy16(Ag + a192 + (ko), &As[buf][12288 + sod]);     \
  async_copy16(Bg + (ko), &Bs[buf][sod]);                    \
  async_copy16(Bg + b64 + (ko), &Bs[buf][4096 + sod]);

    const int niter = K >> 6;
    STAGE6(0, 0);
    STAGE6(1, 64);

    const int rbx = lm & 7;
    const int sl0 = (quad ^ rbx) * 8;          // ks=0 slot offset
    const int sl1 = ((4 + quad) ^ rbx) * 8;    // ks=1 slot offset
    const int arow = wr * 4096 + lm * 64;      // + i*1024
    const int brow = wc * 4096 + lm * 64;

    int cur = 0;
    for (int it = 0; it < niter; ++it) {
      if (it + 1 < niter) {
        asm volatile("s_waitcnt vmcnt(6)\n\ts_barrier" ::: "memory");
      } else {
        asm volatile("s_waitcnt vmcnt(0)\n\ts_barrier" ::: "memory");
      }
      if (it + 2 < niter) {
        const int nb = (cur >= 1) ? cur - 1 : 2;   // (it+2)%3
        const int ko = (it + 2) << 6;
        STAGE6(nb, ko);
      }
      bf16x8 af[4][2], bfr[4][2];
#pragma unroll
      for (int i = 0; i < 4; i++) {
        af[i][0] = *(const bf16x8*)&As[cur][arow + i * 1024 + sl0];
        af[i][1] = *(const bf16x8*)&As[cur][arow + i * 1024 + sl1];
        bfr[i][0] = *(const bf16x8*)&Bs[cur][brow + i * 1024 + sl0];
        bfr[i][1] = *(const bf16x8*)&Bs[cur][brow + i * 1024 + sl1];
      }
      __builtin_amdgcn_s_setprio(1);
#pragma unroll
      for (int ks = 0; ks < 2; ks++)
#pragma unroll
        for (int mi = 0; mi < 4; mi++)
#pragma unroll
          for (int ni = 0; ni < 4; ni++)
            acc[mi][ni] = __builtin_amdgcn_mfma_f32_16x16x32_bf16(
                af[mi][ks], bfr[ni][ks], acc[mi][ni], 0, 0, 0);
      __builtin_amdgcn_s_setprio(0);
      cur = (cur == 2) ? 0 : cur + 1;
    }
#undef STAGE6

    const size_t cz = (size_t)z * sCz;
#pragma unroll
    for (int mi = 0; mi < 4; mi++) {
#pragma unroll
      for (int ni = 0; ni < 4; ni++) {
#pragma unroll
        for (int r = 0; r < 4; r++) {
          int row = m0 + wr * 64 + mi * 16 + quad * 4 + r;
          int col = n0 + wc * 64 + ni * 16 + lm;
          float v = acc[mi][ni][r];
          size_t idx = cz + (size_t)row * ldc + col;
          if (EPI == 1) {
            ((float*)Cv)[idx] = v * scale;
          } else if (EPI == 0) {
            if (bias) v += bias[col];
            ((bf16_t*)Cv)[idx] = (__bf16)v;
          } else if (EPI == 3) {
            v += bias[col];
            float u = 1.5957691216f * (v + 0.044715f * v * v * v);
            float g = v / (1.0f + __expf(-u));
            ((bf16_t*)Cv)[idx] = (__bf16)g;
          }
        }
      }
    }
  }
}

// ---------------- Wo split-K reduce + residual + LN2 + modulate ----------------
__global__ __launch_bounds__(256) void reduce_ln(
    const float* __restrict__ part, const float* __restrict__ x,
    const float* __restrict__ bo, const float* __restrict__ mod,
    float* __restrict__ x1, bf16_t* __restrict__ h) {
  const int row = blockIdx.x;
  const int b = row >> 10;
  const int t = threadIdx.x;
  const int c = t * 4;
  const size_t idx = (size_t)row * 1024 + c;
  float4 p0 = *(const float4*)(part + idx);
  float4 p1 = *(const float4*)(part + 4194304 + idx);
  float4 bb = *(const float4*)(bo + c);
  float4 al = *(const float4*)(mod + (size_t)b * 6144 + 2048 + c);
  float4 xs = *(const float4*)(x + idx);
  float4 xv;
  xv.x = xs.x + al.x * (p0.x + p1.x + bb.x);
  xv.y = xs.y + al.y * (p0.y + p1.y + bb.y);
  xv.z = xs.z + al.z * (p0.z + p1.z + bb.z);
  xv.w = xs.w + al.w * (p0.w + p1.w + bb.w);
  *(float4*)(x1 + idx) = xv;

  float s = xv.x + xv.y + xv.z + xv.w;
  float q = xv.x*xv.x + xv.y*xv.y + xv.z*xv.z + xv.w*xv.w;
  const int wave = t >> 6, lane = t & 63;
#pragma unroll
  for (int offs = 32; offs; offs >>= 1) {
    s += __shfl_down(s, offs);
    q += __shfl_down(q, offs);
  }
  __shared__ float sb[4][2];
  if (lane == 0) { sb[wave][0] = s; sb[wave][1] = q; }
  __syncthreads();
  float st = sb[0][0] + sb[1][0] + sb[2][0] + sb[3][0];
  float qt = sb[0][1] + sb[1][1] + sb[2][1] + sb[3][1];
  float mu = st * (1.0f / D_);
  float var = qt * (1.0f / D_) - mu * mu;
  float rstd = rsqrtf(var + 1e-6f);
  const float* mb = mod + (size_t)b * 6144 + 3072;
  float4 gm = *(const float4*)(mb + c);
  float4 bt = *(const float4*)(mb + 1024 + c);
  bf16x4 pk;
  pk.x = (__bf16)((xv.x - mu) * rstd * (1.0f + bt.x) + gm.x);
  pk.y = (__bf16)((xv.y - mu) * rstd * (1.0f + bt.y) + gm.y);
  pk.z = (__bf16)((xv.z - mu) * rstd * (1.0f + bt.z) + gm.z);
  pk.w = (__bf16)((xv.w - mu) * rstd * (1.0f + bt.w) + gm.w);
  *(bf16x4*)(h + idx) = pk;
}

// ---------------- W2 split-K(2) reduction + epilogue ----------------
__global__ __launch_bounds__(256) void reduce_w2(
    const float* __restrict__ part, const float* __restrict__ x1,
    const float* __restrict__ b2, const float* __restrict__ mod,
    float* __restrict__ out) {
  const int idx = (blockIdx.x * 256 + threadIdx.x) * 4;
  const int col = idx & 1023;
  const int row = idx >> 10;
  const int b = row >> 10;
  float4 s0 = *(const float4*)(part + idx);
  float4 s1 = *(const float4*)(part + 4194304 + idx);
  float4 bb = *(const float4*)(b2 + col);
  float4 al = *(const float4*)(mod + (size_t)b * 6144 + 5120 + col);
  float4 rs = *(const float4*)(x1 + idx);
  float4 o;
  o.x = rs.x + al.x * (s0.x + s1.x + bb.x);
  o.y = rs.y + al.y * (s0.y + s1.y + bb.y);
  o.z = rs.z + al.z * (s0.z + s1.z + bb.z);
  o.w = rs.w + al.w * (s0.w + s1.w + bb.w);
  *(float4*)(out + idx) = o;
}

extern "C" void kernel_launch(void* const* d_in, const int* in_sizes, int n_in,
                              void* d_out, int out_size, void* d_ws, size_t ws_size,
                              hipStream_t stream) {
  (void)in_sizes; (void)n_in; (void)out_size; (void)ws_size;
  const float* x    = (const float*)d_in[0];
  const float* cond = (const float*)d_in[1];
  const float* Wq   = (const float*)d_in[2];
  const float* bq   = (const float*)d_in[3];
  const float* Wk   = (const float*)d_in[4];
  const float* bk   = (const float*)d_in[5];
  const float* Wv   = (const float*)d_in[6];
  const float* bv   = (const float*)d_in[7];
  const float* Wo   = (const float*)d_in[8];
  const float* bo   = (const float*)d_in[9];
  const float* W1   = (const float*)d_in[10];
  const float* b1   = (const float*)d_in[11];
  const float* W2   = (const float*)d_in[12];
  const float* b2   = (const float*)d_in[13];
  const float* Wada = (const float*)d_in[14];
  const float* bada = (const float*)d_in[15];

  uint8_t* ws = (uint8_t*)d_ws;
  bf16_t* wbf   = (bf16_t*)(ws + OFF_WBF);
  float*  bqkv  = (float*)(ws + OFF_BQKV);
  float*  mod   = (float*)(ws + OFF_MOD);
  bf16_t* h     = (bf16_t*)(ws + OFF_H);
  bf16_t* qkv   = (bf16_t*)(ws + OFF_QKV);
  bf16_t* vT    = (bf16_t*)(ws + OFF_VT);
  bf16_t* attn  = (bf16_t*)(ws + OFF_ATTN);
  float*  x1    = (float*)(ws + OFF_X1);
  float*  part  = (float*)(ws + OFF_PART);
  bf16_t* mlph  = (bf16_t*)(ws + OFF_MLPH);
  float* out = (float*)d_out;

  convert_pack<<<dim3(4096, 7, 1), 256, 0, stream>>>(Wq, Wk, Wv, Wo, W1, W2,
                                                     bq, bk, bv, wbf, bqkv);
  ada_mod<<<1536, 256, 0, stream>>>(cond, Wada, bada, mod);
  ln_modulate<<<4096, 256, 0, stream>>>(x, mod, h, 0);
  // qkv = h @ [Wq;Wk;Wv]^T + bias   (M=4096, N=3072, K=1024) grid 24x16=384
  gemm_bt<0><<<dim3(24, 16, 1), 512, 0, stream>>>(
      h, 1024, 0, wbf, 1024, 0, qkv, 3072, 0, 4096, 3072, 1024,
      bqkv, 1.f);
  transpose_v<<<dim3(16, 64, 1), 256, 0, stream>>>(qkv, vT);
  flash_attn<<<dim3(8, 64, 1), 512, 0, stream>>>(qkv, vT, attn);

  // Wo split-K=2: part[z] = attn[:, z*512:] @ Wo[:, z*512:]^T  grid 8x16x2=256
  gemm_bt<1><<<dim3(8, 16, 2), 512, 0, stream>>>(
      attn, 1024, 512, wbf + (size_t)3 * MEG, 1024, 512, part, 1024, 4194304,
      4096, 1024, 512, nullptr, 1.f);
  // x1 = x + alpha1*(sum part + bo); h = modulate(ln(x1), beta2, gama2)
  reduce_ln<<<4096, 256, 0, stream>>>(part, x, bo, mod, x1, h);

  // mlph = gelu(h @ W1^T + b1)   (M=4096, N=4096, K=1024) grid 32x16=512
  gemm_bt<3><<<dim3(32, 16, 1), 512, 0, stream>>>(
      h, 1024, 0, wbf + (size_t)4 * MEG, 1024, 0, mlph, 4096, 0,
      4096, 4096, 1024, b1, 1.f);
  // W2 split-K=2  (M=4096, N=1024, K=2048 per z) grid 8x16x2=256
  gemm_bt<1><<<dim3(8, 16, 2), 512, 0, stream>>>(
      mlph, 4096, 2048, wbf + (size_t)8 * MEG, 4096, 2048, part, 1024, 4194304,
      4096, 1024, 2048, nullptr, 1.f);
  reduce_w2<<<4096, 256, 0, stream>>>(part, x1, b2, mod, out);
}

// Round 6
// 390.770 us; speedup vs baseline: 1.0556x; 1.0556x over previous
//
#include <hip/hip_runtime.h>
#include <cstdint>

typedef __bf16 bf16_t;
typedef __bf16 bf16x4 __attribute__((ext_vector_type(4)));
typedef __bf16 bf16x8 __attribute__((ext_vector_type(8)));
typedef float f32x4 __attribute__((ext_vector_type(4)));

#define B_ 4
#define S_ 1024
#define D_ 1024
#define HID_ 4096
#define MEG (1u << 20)

// ---------------- workspace layout (bytes) ----------------
static const size_t OFF_WBF  = 0;                 // 12M bf16 (Wq,Wk,Wv,Wo,W1,W2)
static const size_t OFF_BQKV = 25165824;          // 3072 f32
static const size_t OFF_MOD  = 25178112;          // 4*6144 f32
static const size_t OFF_H    = 25276416;          // 4096*1024 bf16
static const size_t OFF_QKV  = 33665024;          // 4096*3072 bf16
static const size_t OFF_VT   = 58830848;          // 4*16*64*1024 bf16
static const size_t OFF_ATTN = 67219456;          // 4096*1024 bf16
static const size_t OFF_X1   = 75608064;          // 4096*1024 f32
static const size_t OFF_PART = 92385280;          // 2 * 4096*1024 f32 (split-K partials)
static const size_t OFF_MLPH = 159494144;         // 4096*4096 bf16 = 32MB

// ---------------- async global->LDS (16B/lane) ----------------
__device__ __forceinline__ void async_copy16(const bf16_t* g, bf16_t* l) {
  __builtin_amdgcn_global_load_lds(
      (__attribute__((address_space(1))) void*)(g),
      (__attribute__((address_space(3))) void*)(l), 16, 0, 0);
}

// ---------------- weight convert + bias pack ----------------
__global__ __launch_bounds__(256) void convert_pack(
    const float* __restrict__ Wq, const float* __restrict__ Wk,
    const float* __restrict__ Wv, const float* __restrict__ Wo,
    const float* __restrict__ W1, const float* __restrict__ W2,
    const float* __restrict__ bq, const float* __restrict__ bk,
    const float* __restrict__ bv, bf16_t* __restrict__ wbf,
    float* __restrict__ bqkv) {
  const int y = blockIdx.y;
  if (y == 6) {
    int i = blockIdx.x * 256 + threadIdx.x;
    if (i < 3072)
      bqkv[i] = i < 1024 ? bq[i] : (i < 2048 ? bk[i - 1024] : bv[i - 2048]);
    return;
  }
  const float* src; bf16_t* dst; int n;
  switch (y) {
    case 0: src = Wq; dst = wbf;           n = MEG;     break;
    case 1: src = Wk; dst = wbf + MEG;     n = MEG;     break;
    case 2: src = Wv; dst = wbf + 2*MEG;   n = MEG;     break;
    case 3: src = Wo; dst = wbf + 3*MEG;   n = MEG;     break;
    case 4: src = W1; dst = wbf + 4*MEG;   n = 4*MEG;   break;
    default: src = W2; dst = wbf + 8*MEG;  n = 4*MEG;   break;
  }
  int idx = (blockIdx.x * 256 + threadIdx.x) * 4;
  if (idx < n) {
    float4 v = *(const float4*)(src + idx);
    bf16x4 pk;
    pk.x = (__bf16)v.x; pk.y = (__bf16)v.y; pk.z = (__bf16)v.z; pk.w = (__bf16)v.w;
    *(bf16x4*)(dst + idx) = pk;
  }
}

// ---------------- adaLN: one wave per output o, all 4 batches ----------------
__global__ __launch_bounds__(256) void ada_mod(
    const float* __restrict__ cond, const float* __restrict__ Wada,
    const float* __restrict__ bada, float* __restrict__ mod) {
  const int wave = threadIdx.x >> 6, lane = threadIdx.x & 63;
  const int o = blockIdx.x * 4 + wave;      // 0..6143
  const float* wr = Wada + (size_t)o * D_;
  float a0 = 0.f, a1 = 0.f, a2 = 0.f, a3 = 0.f;
#pragma unroll
  for (int l = 0; l < 16; l++) {
    int i = l * 64 + lane;
    float w = wr[i];
    float c0 = cond[i], c1 = cond[1024 + i], c2 = cond[2048 + i], c3 = cond[3072 + i];
    a0 += w * (c0 / (1.0f + __expf(-c0)));
    a1 += w * (c1 / (1.0f + __expf(-c1)));
    a2 += w * (c2 / (1.0f + __expf(-c2)));
    a3 += w * (c3 / (1.0f + __expf(-c3)));
  }
#pragma unroll
  for (int offs = 32; offs; offs >>= 1) {
    a0 += __shfl_xor(a0, offs);
    a1 += __shfl_xor(a1, offs);
    a2 += __shfl_xor(a2, offs);
    a3 += __shfl_xor(a3, offs);
  }
  if (lane == 0) {
    float bb = bada[o];
    mod[o]          = a0 + bb;
    mod[6144 + o]   = a1 + bb;
    mod[12288 + o]  = a2 + bb;
    mod[18432 + o]  = a3 + bb;
  }
}

// ---------------- LayerNorm + modulate -> bf16 ----------------
__global__ __launch_bounds__(256) void ln_modulate(
    const float* __restrict__ X, const float* __restrict__ mod,
    bf16_t* __restrict__ H, int goff) {
  const int row = blockIdx.x;
  const int b = row >> 10;
  const int t = threadIdx.x;
  const float* xr = X + (size_t)row * D_;
  float4 xv = *(const float4*)(xr + t * 4);
  float s = xv.x + xv.y + xv.z + xv.w;
  float q = xv.x*xv.x + xv.y*xv.y + xv.z*xv.z + xv.w*xv.w;
  const int wave = t >> 6, lane = t & 63;
#pragma unroll
  for (int offs = 32; offs; offs >>= 1) {
    s += __shfl_down(s, offs);
    q += __shfl_down(q, offs);
  }
  __shared__ float sb[4][2];
  if (lane == 0) { sb[wave][0] = s; sb[wave][1] = q; }
  __syncthreads();
  float st = sb[0][0] + sb[1][0] + sb[2][0] + sb[3][0];
  float qt = sb[0][1] + sb[1][1] + sb[2][1] + sb[3][1];
  float mu = st * (1.0f / D_);
  float var = qt * (1.0f / D_) - mu * mu;
  float rstd = rsqrtf(var + 1e-6f);
  const float* mb = mod + (size_t)b * 6144 + goff;
  const int c = t * 4;
  float4 gm = *(const float4*)(mb + c);
  float4 bt = *(const float4*)(mb + 1024 + c);
  bf16x4 pk;
  pk.x = (__bf16)((xv.x - mu) * rstd * (1.0f + bt.x) + gm.x);
  pk.y = (__bf16)((xv.y - mu) * rstd * (1.0f + bt.y) + gm.y);
  pk.z = (__bf16)((xv.z - mu) * rstd * (1.0f + bt.z) + gm.z);
  pk.w = (__bf16)((xv.w - mu) * rstd * (1.0f + bt.w) + gm.w);
  *(bf16x4*)(H + (size_t)row * D_ + c) = pk;
}

// ---------------- V transpose: vT[b,h,d,s] <- qkv[b,s, 2048+h*64+d] ----------------
__global__ __launch_bounds__(256) void transpose_v(
    const bf16_t* __restrict__ qkv, bf16_t* __restrict__ vT) {
  __shared__ bf16_t tile[64][65];
  const int bh = blockIdx.y;
  const int b = bh >> 4, hh = bh & 15;
  const int s0 = blockIdx.x * 64;
  const int t = threadIdx.x;
  const int tx = t & 63, ty = t >> 6;
  const bf16_t* src = qkv + (size_t)b * S_ * 3072 + 2048 + hh * 64;
  for (int r = ty; r < 64; r += 4)
    tile[r][tx] = src[(size_t)(s0 + r) * 3072 + tx];
  __syncthreads();
  bf16_t* dst = vT + (size_t)bh * 64 * 1024;
  for (int r = ty; r < 64; r += 4)
    dst[(size_t)r * 1024 + s0 + tx] = tile[tx][r];
}

// ---------------- flash attention (v4) ----------------
// QBLK=128, 512 threads (8 waves); K/V LDS shared; KBLK=128 softmax
// granularity; dbuf prefetch before compute; deferred cross-lane sum.
// LDS = 80KB -> 2 blocks/CU = 16 waves/CU.
__global__ __launch_bounds__(512, 4) void flash_attn(
    const bf16_t* __restrict__ qkv, const bf16_t* __restrict__ vT,
    bf16_t* __restrict__ attn) {
  __shared__ __align__(16) bf16_t Ks[2][2][64 * 64];
  __shared__ __align__(16) bf16_t Vs[2][2][64 * 64];
  __shared__ __align__(16) bf16_t Ps[8][16 * 64];

  const int t = threadIdx.x;
  const int wave = t >> 6, lane = t & 63;
  const int lm = lane & 15, quad = lane >> 4;
  const int bh = blockIdx.y;
  const int b = bh >> 4, hh = bh & 15;
  const int s0 = blockIdx.x * 128;

  const bf16_t* qbase = qkv + (size_t)b * S_ * 3072 + hh * 64;
  const bf16_t* kbase = qbase + 1024;
  const bf16_t* vbase = vT + (size_t)bh * (64 * 1024);

  const int row0 = t >> 3;            // 0..63
  const int cg = (t & 7) ^ (row0 & 7);
  const int od = t * 8;               // LDS element offset

  async_copy16(qbase + (size_t)(s0 + row0) * 3072 + cg * 8, &Ks[1][0][od]);
  async_copy16(qbase + (size_t)(s0 + 64 + row0) * 3072 + cg * 8, &Ks[1][1][od]);
  async_copy16(kbase + (size_t)row0 * 3072 + cg * 8, &Ks[0][0][od]);
  async_copy16(kbase + (size_t)(64 + row0) * 3072 + cg * 8, &Ks[0][1][od]);
  async_copy16(vbase + (size_t)row0 * 1024 + cg * 8, &Vs[0][0][od]);
  async_copy16(vbase + (size_t)row0 * 1024 + 64 + cg * 8, &Vs[0][1][od]);
  __syncthreads();

  bf16x8 aq0, aq1;
  {
    const int rq = wave * 16 + lm;
    const int qh = rq >> 6, qr = rq & 63;
    const int rbq = lm & 7;
    aq0 = *(const bf16x8*)&Ks[1][qh][qr * 64 + (quad ^ rbq) * 8];
    aq1 = *(const bf16x8*)&Ks[1][qh][qr * 64 + ((4 + quad) ^ rbq) * 8];
  }
  __syncthreads();

  f32x4 accO[4] = {};
  float mrow[4], lsum[4];
#pragma unroll
  for (int r = 0; r < 4; r++) { mrow[r] = -1e30f; lsum[r] = 0.f; }

  const float SC = 0.18033688f;         // 0.125 * log2(e): exp2 domain
  const int rb = lm & 7;
  bf16_t* Pw = Ps[wave];

  for (int tt = 0; tt < 8; ++tt) {
    const int cur = tt & 1;
    if (tt < 7) {
      const int nb = cur ^ 1;
      const size_t k0n = (size_t)(tt + 1) << 7;
      async_copy16(kbase + (k0n + row0) * 3072 + cg * 8, &Ks[nb][0][od]);
      async_copy16(kbase + (k0n + 64 + row0) * 3072 + cg * 8, &Ks[nb][1][od]);
      async_copy16(vbase + (size_t)row0 * 1024 + k0n + cg * 8, &Vs[nb][0][od]);
      async_copy16(vbase + (size_t)row0 * 1024 + k0n + 64 + cg * 8, &Vs[nb][1][od]);
    }

    f32x4 accS[8];
#pragma unroll
    for (int j = 0; j < 8; j++) accS[j] = (f32x4){0.f, 0.f, 0.f, 0.f};
    __builtin_amdgcn_s_setprio(1);
#pragma unroll
    for (int hf = 0; hf < 2; hf++) {
#pragma unroll
      for (int ni = 0; ni < 4; ni++) {
        const int rk = ni * 16 + lm;
        bf16x8 b0 = *(const bf16x8*)&Ks[cur][hf][rk * 64 + ((quad ^ rb)) * 8];
        bf16x8 b1 = *(const bf16x8*)&Ks[cur][hf][rk * 64 + (((4 + quad) ^ rb)) * 8];
        f32x4 a = accS[hf * 4 + ni];
        a = __builtin_amdgcn_mfma_f32_16x16x32_bf16(aq0, b0, a, 0, 0, 0);
        a = __builtin_amdgcn_mfma_f32_16x16x32_bf16(aq1, b1, a, 0, 0, 0);
        accS[hf * 4 + ni] = a;
      }
    }
    __builtin_amdgcn_s_setprio(0);

    float mx[4];
#pragma unroll
    for (int r = 0; r < 4; r++) {
      float m0 = fmaxf(fmaxf(accS[0][r], accS[1][r]), fmaxf(accS[2][r], accS[3][r]));
      float m1 = fmaxf(fmaxf(accS[4][r], accS[5][r]), fmaxf(accS[6][r], accS[7][r]));
      float m8 = fmaxf(m0, m1);
      m8 = fmaxf(m8, __shfl_xor(m8, 1));
      m8 = fmaxf(m8, __shfl_xor(m8, 2));
      m8 = fmaxf(m8, __shfl_xor(m8, 4));
      m8 = fmaxf(m8, __shfl_xor(m8, 8));
      mx[r] = m8 * SC;
    }
    bool ok = (mx[0] - mrow[0] <= 8.0f) && (mx[1] - mrow[1] <= 8.0f) &&
              (mx[2] - mrow[2] <= 8.0f) && (mx[3] - mrow[3] <= 8.0f);
    if (!__all(ok)) {
#pragma unroll
      for (int r = 0; r < 4; r++) {
        float mnew = fmaxf(mrow[r], mx[r]);
        float al = exp2f(mrow[r] - mnew);
        mrow[r] = mnew;
        lsum[r] *= al;
#pragma unroll
        for (int di = 0; di < 4; di++) accO[di][r] *= al;
      }
    }
#pragma unroll
    for (int r = 0; r < 4; r++) {
      float sum = 0.f;
#pragma unroll
      for (int j = 0; j < 8; j++) {
        float p = exp2f(accS[j][r] * SC - mrow[r]);
        accS[j][r] = p;
        sum += p;
      }
      lsum[r] += sum;
    }

#pragma unroll
    for (int hf = 0; hf < 2; hf++) {
#pragma unroll
      for (int jj = 0; jj < 4; jj++)
#pragma unroll
        for (int r = 0; r < 4; r++) {
          int prow = quad * 4 + r;
          int c = jj * 16 + lm;
          Pw[prow * 64 + (((c >> 3) ^ (prow & 7)) << 3) + (c & 7)] =
              (__bf16)accS[hf * 4 + jj][r];
        }
      __builtin_amdgcn_s_setprio(1);
#pragma unroll
      for (int loc = 0; loc < 2; loc++) {
        bf16x8 ap = *(const bf16x8*)&Pw[lm * 64 + (((loc * 4 + quad) ^ rb)) * 8];
#pragma unroll
        for (int di = 0; di < 4; di++) {
          const int rv = di * 16 + lm;
          bf16x8 vv = *(const bf16x8*)&Vs[cur][hf]
              [rv * 64 + (((loc * 4 + quad) ^ rb)) * 8];
          accO[di] = __builtin_amdgcn_mfma_f32_16x16x32_bf16(ap, vv, accO[di], 0, 0, 0);
        }
      }
      __builtin_amdgcn_s_setprio(0);
    }
    __syncthreads();
  }

#pragma unroll
  for (int r = 0; r < 4; r++) {
    float sv = lsum[r];
    sv += __shfl_xor(sv, 1);
    sv += __shfl_xor(sv, 2);
    sv += __shfl_xor(sv, 4);
    sv += __shfl_xor(sv, 8);
    lsum[r] = sv;
  }

#pragma unroll
  for (int r = 0; r < 4; r++) {
    float inv = 1.0f / lsum[r];
    int prow = quad * 4 + r;
#pragma unroll
    for (int di = 0; di < 4; di++) {
      int col = di * 16 + lm;
      int cph = (col >> 3) ^ (prow & 7);
      Pw[prow * 64 + cph * 8 + (col & 7)] = (__bf16)(accO[di][r] * inv);
    }
  }
  bf16_t* abase = attn + (size_t)b * S_ * 1024 +
                  (size_t)(s0 + wave * 16) * 1024 + hh * 64;
#pragma unroll
  for (int it = 0; it < 2; it++) {
    int slot = it * 64 + lane;
    int orow = slot >> 3;
    int gc = slot & 7;
    int cph = gc ^ (orow & 7);
    bf16x8 val = *(const bf16x8*)&Pw[orow * 64 + cph * 8];
    *(bf16x8*)(abase + (size_t)orow * 1024 + gc * 8) = val;
  }
}

// ---------------- C = A * B^T GEMM v7: phase-split schedule -------------------
// 512 threads, BM=256 BN=128 BK=64, 8 waves (4M x 2N), per-wave 64x64.
// Ring-of-3 LDS (144KB), staged 2 K-tiles ahead, counted vmcnt(6).
// NEW vs v6: each K-tile split into 2 phases of 16 MFMA with the 8-phase
// template's double-barrier rhythm:
//   phase A: {ds_read af0,af1 + all 8 B-frags; 3 stage loads; barrier;
//             setprio(1); 16 MFMA (mi=0,1); setprio(0); barrier}
//   phase B: {ds_read af2,af3; 3 stage loads; barrier; 16 MFMA (mi=2,3)}
// so ds_read/stage issue of one phase overlaps the other waves' MFMA cluster.
// Addressing, swizzle (0 conflicts), epilogue identical to verified v6.
// M mult of 256; N mult of 128; K mult of 64; grid blocks mult of 8.
// EPI: 0 = (+bias) -> bf16 ; 1 = identity -> f32 ; 3 = gelu(acc+bias) -> bf16
template <int EPI>
__global__ __launch_bounds__(512) void gemm_bt(
    const bf16_t* __restrict__ A, int lda, long long sAz,
    const bf16_t* __restrict__ B, int ldb, long long sBz,
    void* __restrict__ Cv, int ldc, long long sCz,
    int M, int N, int K,
    const float* __restrict__ bias,
    float scale) {
  __shared__ __align__(16) bf16_t As[3][256 * 64];   // 96KB
  __shared__ __align__(16) bf16_t Bs[3][128 * 64];   // 48KB

  const int z = blockIdx.z;
  A += (size_t)z * sAz;
  B += (size_t)z * sBz;

  const int gx = gridDim.x;
  int d = blockIdx.x + gx * blockIdx.y;
  {
    const int cpx = (gx * gridDim.y) >> 3;
    int wg = (d & 7) * cpx + (d >> 3);
    const int by = wg / gx;     // M-tile
    const int bx = wg % gx;     // N-tile

    const int t = threadIdx.x;
    const int wave = t >> 6;
    const int lane = t & 63;
    const int lm = lane & 15;
    const int quad = lane >> 4;
    const int wr = wave >> 1;   // 0..3: M sub-block
    const int wc = wave & 1;    // 0..1: N sub-block

    const int m0 = by * 256;
    const int n0 = bx * 128;

    f32x4 acc[4][4] = {};

    // staging: unit = 64 rows x 64 cols (8KB); thread t -> row t>>3,
    // LDS slot t&7 holds global chunk (t&7)^(row&7)
    const int srow = t >> 3;                    // 0..63
    const int scg = (t & 7) ^ (srow & 7);
    const int sod = t * 8;                      // LDS elem offset in unit
    const bf16_t* Ag = A + (size_t)(m0 + srow) * lda + scg * 8;
    const bf16_t* Bg = B + (size_t)(n0 + srow) * ldb + scg * 8;
    const size_t a64 = (size_t)64 * lda, a128 = (size_t)128 * lda,
                 a192 = (size_t)192 * lda, b64 = (size_t)64 * ldb;

#define STAGE6(buf, ko)                                      \
  async_copy16(Ag + (ko), &As[buf][sod]);                    \
  async_copy16(Ag + a64 + (ko), &As[buf][4096 + sod]);       \
  async_copy16(Ag + a128 + (ko), &As[buf][8192 + sod]);      \
  async_copy16(Ag + a192 + (ko), &As[buf][12288 + sod]);     \
  async_copy16(Bg + (ko), &Bs[buf][sod]);                    \
  async_copy16(Bg + b64 + (ko), &Bs[buf][4096 + sod]);

    const int niter = K >> 6;
    STAGE6(0, 0);
    STAGE6(1, 64);

    const int rbx = lm & 7;
    const int sl0 = (quad ^ rbx) * 8;          // ks=0 slot offset
    const int sl1 = ((4 + quad) ^ rbx) * 8;    // ks=1 slot offset
    const int arow = wr * 4096 + lm * 64;      // + mi*1024
    const int brow = wc * 4096 + lm * 64;

    int cur = 0;
    for (int it = 0; it < niter; ++it) {
      if (it + 1 < niter) {
        asm volatile("s_waitcnt vmcnt(6)" ::: "memory");
      } else {
        asm volatile("s_waitcnt vmcnt(0)" ::: "memory");
      }
      __builtin_amdgcn_s_barrier();            // buf[cur] ready for all waves
      const int nb = (cur >= 1) ? cur - 1 : 2; // ring slot for tile it+2
      const int ko = (it + 2) << 6;
      const bool st = (it + 2 < niter);

      // ---------------- phase A ----------------
      bf16x8 af0[2], af1[2], bfr[4][2];
      af0[0] = *(const bf16x8*)&As[cur][arow + sl0];
      af0[1] = *(const bf16x8*)&As[cur][arow + sl1];
      af1[0] = *(const bf16x8*)&As[cur][arow + 1024 + sl0];
      af1[1] = *(const bf16x8*)&As[cur][arow + 1024 + sl1];
#pragma unroll
      for (int i = 0; i < 4; i++) {
        bfr[i][0] = *(const bf16x8*)&Bs[cur][brow + i * 1024 + sl0];
        bfr[i][1] = *(const bf16x8*)&Bs[cur][brow + i * 1024 + sl1];
      }
      if (st) {
        async_copy16(Ag + ko, &As[nb][sod]);
        async_copy16(Ag + a64 + ko, &As[nb][4096 + sod]);
        async_copy16(Ag + a128 + ko, &As[nb][8192 + sod]);
      }
      __builtin_amdgcn_s_barrier();
      __builtin_amdgcn_s_setprio(1);
#pragma unroll
      for (int ks = 0; ks < 2; ks++)
#pragma unroll
        for (int ni = 0; ni < 4; ni++) {
          acc[0][ni] = __builtin_amdgcn_mfma_f32_16x16x32_bf16(
              af0[ks], bfr[ni][ks], acc[0][ni], 0, 0, 0);
          acc[1][ni] = __builtin_amdgcn_mfma_f32_16x16x32_bf16(
              af1[ks], bfr[ni][ks], acc[1][ni], 0, 0, 0);
        }
      __builtin_amdgcn_s_setprio(0);
      __builtin_amdgcn_s_barrier();

      // ---------------- phase B ----------------
      bf16x8 af2[2], af3[2];
      af2[0] = *(const bf16x8*)&As[cur][arow + 2048 + sl0];
      af2[1] = *(const bf16x8*)&As[cur][arow + 2048 + sl1];
      af3[0] = *(const bf16x8*)&As[cur][arow + 3072 + sl0];
      af3[1] = *(const bf16x8*)&As[cur][arow + 3072 + sl1];
      if (st) {
        async_copy16(Ag + a192 + ko, &As[nb][12288 + sod]);
        async_copy16(Bg + ko, &Bs[nb][sod]);
        async_copy16(Bg + b64 + ko, &Bs[nb][4096 + sod]);
      }
      __builtin_amdgcn_s_barrier();
      __builtin_amdgcn_s_setprio(1);
#pragma unroll
      for (int ks = 0; ks < 2; ks++)
#pragma unroll
        for (int ni = 0; ni < 4; ni++) {
          acc[2][ni] = __builtin_amdgcn_mfma_f32_16x16x32_bf16(
              af2[ks], bfr[ni][ks], acc[2][ni], 0, 0, 0);
          acc[3][ni] = __builtin_amdgcn_mfma_f32_16x16x32_bf16(
              af3[ks], bfr[ni][ks], acc[3][ni], 0, 0, 0);
        }
      __builtin_amdgcn_s_setprio(0);
      cur = (cur == 2) ? 0 : cur + 1;
    }
#undef STAGE6

    const size_t cz = (size_t)z * sCz;
#pragma unroll
    for (int mi = 0; mi < 4; mi++) {
#pragma unroll
      for (int ni = 0; ni < 4; ni++) {
#pragma unroll
        for (int r = 0; r < 4; r++) {
          int row = m0 + wr * 64 + mi * 16 + quad * 4 + r;
          int col = n0 + wc * 64 + ni * 16 + lm;
          float v = acc[mi][ni][r];
          size_t idx = cz + (size_t)row * ldc + col;
          if (EPI == 1) {
            ((float*)Cv)[idx] = v * scale;
          } else if (EPI == 0) {
            if (bias) v += bias[col];
            ((bf16_t*)Cv)[idx] = (__bf16)v;
          } else if (EPI == 3) {
            v += bias[col];
            float u = 1.5957691216f * (v + 0.044715f * v * v * v);
            float g = v / (1.0f + __expf(-u));
            ((bf16_t*)Cv)[idx] = (__bf16)g;
          }
        }
      }
    }
  }
}

// ---------------- Wo split-K reduce + residual + LN2 + modulate ----------------
__global__ __launch_bounds__(256) void reduce_ln(
    const float* __restrict__ part, const float* __restrict__ x,
    const float* __restrict__ bo, const float* __restrict__ mod,
    float* __restrict__ x1, bf16_t* __restrict__ h) {
  const int row = blockIdx.x;
  const int b = row >> 10;
  const int t = threadIdx.x;
  const int c = t * 4;
  const size_t idx = (size_t)row * 1024 + c;
  float4 p0 = *(const float4*)(part + idx);
  float4 p1 = *(const float4*)(part + 4194304 + idx);
  float4 bb = *(const float4*)(bo + c);
  float4 al = *(const float4*)(mod + (size_t)b * 6144 + 2048 + c);
  float4 xs = *(const float4*)(x + idx);
  float4 xv;
  xv.x = xs.x + al.x * (p0.x + p1.x + bb.x);
  xv.y = xs.y + al.y * (p0.y + p1.y + bb.y);
  xv.z = xs.z + al.z * (p0.z + p1.z + bb.z);
  xv.w = xs.w + al.w * (p0.w + p1.w + bb.w);
  *(float4*)(x1 + idx) = xv;

  float s = xv.x + xv.y + xv.z + xv.w;
  float q = xv.x*xv.x + xv.y*xv.y + xv.z*xv.z + xv.w*xv.w;
  const int wave = t >> 6, lane = t & 63;
#pragma unroll
  for (int offs = 32; offs; offs >>= 1) {
    s += __shfl_down(s, offs);
    q += __shfl_down(q, offs);
  }
  __shared__ float sb[4][2];
  if (lane == 0) { sb[wave][0] = s; sb[wave][1] = q; }
  __syncthreads();
  float st = sb[0][0] + sb[1][0] + sb[2][0] + sb[3][0];
  float qt = sb[0][1] + sb[1][1] + sb[2][1] + sb[3][1];
  float mu = st * (1.0f / D_);
  float var = qt * (1.0f / D_) - mu * mu;
  float rstd = rsqrtf(var + 1e-6f);
  const float* mb = mod + (size_t)b * 6144 + 3072;
  float4 gm = *(const float4*)(mb + c);
  float4 bt = *(const float4*)(mb + 1024 + c);
  bf16x4 pk;
  pk.x = (__bf16)((xv.x - mu) * rstd * (1.0f + bt.x) + gm.x);
  pk.y = (__bf16)((xv.y - mu) * rstd * (1.0f + bt.y) + gm.y);
  pk.z = (__bf16)((xv.z - mu) * rstd * (1.0f + bt.z) + gm.z);
  pk.w = (__bf16)((xv.w - mu) * rstd * (1.0f + bt.w) + gm.w);
  *(bf16x4*)(h + idx) = pk;
}

// ---------------- W2 split-K(2) reduction + epilogue ----------------
__global__ __launch_bounds__(256) void reduce_w2(
    const float* __restrict__ part, const float* __restrict__ x1,
    const float* __restrict__ b2, const float* __restrict__ mod,
    float* __restrict__ out) {
  const int idx = (blockIdx.x * 256 + threadIdx.x) * 4;
  const int col = idx & 1023;
  const int row = idx >> 10;
  const int b = row >> 10;
  float4 s0 = *(const float4*)(part + idx);
  float4 s1 = *(const float4*)(part + 4194304 + idx);
  float4 bb = *(const float4*)(b2 + col);
  float4 al = *(const float4*)(mod + (size_t)b * 6144 + 5120 + col);
  float4 rs = *(const float4*)(x1 + idx);
  float4 o;
  o.x = rs.x + al.x * (s0.x + s1.x + bb.x);
  o.y = rs.y + al.y * (s0.y + s1.y + bb.y);
  o.z = rs.z + al.z * (s0.z + s1.z + bb.z);
  o.w = rs.w + al.w * (s0.w + s1.w + bb.w);
  *(float4*)(out + idx) = o;
}

extern "C" void kernel_launch(void* const* d_in, const int* in_sizes, int n_in,
                              void* d_out, int out_size, void* d_ws, size_t ws_size,
                              hipStream_t stream) {
  (void)in_sizes; (void)n_in; (void)out_size; (void)ws_size;
  const float* x    = (const float*)d_in[0];
  const float* cond = (const float*)d_in[1];
  const float* Wq   = (const float*)d_in[2];
  const float* bq   = (const float*)d_in[3];
  const float* Wk   = (const float*)d_in[4];
  const float* bk   = (const float*)d_in[5];
  const float* Wv   = (const float*)d_in[6];
  const float* bv   = (const float*)d_in[7];
  const float* Wo   = (const float*)d_in[8];
  const float* bo   = (const float*)d_in[9];
  const float* W1   = (const float*)d_in[10];
  const float* b1   = (const float*)d_in[11];
  const float* W2   = (const float*)d_in[12];
  const float* b2   = (const float*)d_in[13];
  const float* Wada = (const float*)d_in[14];
  const float* bada = (const float*)d_in[15];

  uint8_t* ws = (uint8_t*)d_ws;
  bf16_t* wbf   = (bf16_t*)(ws + OFF_WBF);
  float*  bqkv  = (float*)(ws + OFF_BQKV);
  float*  mod   = (float*)(ws + OFF_MOD);
  bf16_t* h     = (bf16_t*)(ws + OFF_H);
  bf16_t* qkv   = (bf16_t*)(ws + OFF_QKV);
  bf16_t* vT    = (bf16_t*)(ws + OFF_VT);
  bf16_t* attn  = (bf16_t*)(ws + OFF_ATTN);
  float*  x1    = (float*)(ws + OFF_X1);
  float*  part  = (float*)(ws + OFF_PART);
  bf16_t* mlph  = (bf16_t*)(ws + OFF_MLPH);
  float* out = (float*)d_out;

  convert_pack<<<dim3(4096, 7, 1), 256, 0, stream>>>(Wq, Wk, Wv, Wo, W1, W2,
                                                     bq, bk, bv, wbf, bqkv);
  ada_mod<<<1536, 256, 0, stream>>>(cond, Wada, bada, mod);
  ln_modulate<<<4096, 256, 0, stream>>>(x, mod, h, 0);
  // qkv = h @ [Wq;Wk;Wv]^T + bias   (M=4096, N=3072, K=1024) grid 24x16=384
  gemm_bt<0><<<dim3(24, 16, 1), 512, 0, stream>>>(
      h, 1024, 0, wbf, 1024, 0, qkv, 3072, 0, 4096, 3072, 1024,
      bqkv, 1.f);
  transpose_v<<<dim3(16, 64, 1), 256, 0, stream>>>(qkv, vT);
  flash_attn<<<dim3(8, 64, 1), 512, 0, stream>>>(qkv, vT, attn);

  // Wo split-K=2: part[z] = attn[:, z*512:] @ Wo[:, z*512:]^T  grid 8x16x2
  gemm_bt<1><<<dim3(8, 16, 2), 512, 0, stream>>>(
      attn, 1024, 512, wbf + (size_t)3 * MEG, 1024, 512, part, 1024, 4194304,
      4096, 1024, 512, nullptr, 1.f);
  // x1 = x + alpha1*(sum part + bo); h = modulate(ln(x1), beta2, gama2)
  reduce_ln<<<4096, 256, 0, stream>>>(part, x, bo, mod, x1, h);

  // mlph = gelu(h @ W1^T + b1)   (M=4096, N=4096, K=1024) grid 32x16=512
  gemm_bt<3><<<dim3(32, 16, 1), 512, 0, stream>>>(
      h, 1024, 0, wbf + (size_t)4 * MEG, 1024, 0, mlph, 4096, 0,
      4096, 4096, 1024, b1, 1.f);
  // W2 split-K=2  (M=4096, N=1024, K=2048 per z) grid 8x16x2
  gemm_bt<1><<<dim3(8, 16, 2), 512, 0, stream>>>(
      mlph, 4096, 2048, wbf + (size_t)8 * MEG, 4096, 2048, part, 1024, 4194304,
      4096, 1024, 2048, nullptr, 1.f);
  reduce_w2<<<4096, 256, 0, stream>>>(part, x1, b2, mod, out);
}

// Round 8
// 381.456 us; speedup vs baseline: 1.0813x; 1.0244x over previous
//
#include <hip/hip_runtime.h>
#include <cstdint>

typedef __bf16 bf16_t;
typedef __bf16 bf16x4 __attribute__((ext_vector_type(4)));
typedef __bf16 bf16x8 __attribute__((ext_vector_type(8)));
typedef float f32x4 __attribute__((ext_vector_type(4)));

#define B_ 4
#define S_ 1024
#define D_ 1024
#define HID_ 4096
#define MEG (1u << 20)

// ---------------- workspace layout (bytes) ----------------
static const size_t OFF_WBF  = 0;                 // 12M bf16 (Wq,Wk,Wv,Wo,W1,W2)
static const size_t OFF_BQKV = 25165824;          // 3072 f32
static const size_t OFF_MOD  = 25178112;          // 4*6144 f32
static const size_t OFF_H    = 25276416;          // 4096*1024 bf16
static const size_t OFF_QKV  = 33665024;          // 4096*3072 bf16
static const size_t OFF_VT   = 58830848;          // 4*16*64*1024 bf16
static const size_t OFF_ATTN = 67219456;          // 4096*1024 bf16
static const size_t OFF_X1   = 75608064;          // 4096*1024 f32
static const size_t OFF_PART = 92385280;          // 2 * 4096*1024 f32 (split-K partials)
static const size_t OFF_MLPH = 159494144;         // 4096*4096 bf16 = 32MB

// ---------------- async global->LDS (16B/lane) ----------------
__device__ __forceinline__ void async_copy16(const bf16_t* g, bf16_t* l) {
  __builtin_amdgcn_global_load_lds(
      (__attribute__((address_space(1))) void*)(g),
      (__attribute__((address_space(3))) void*)(l), 16, 0, 0);
}

// ---------------- weight convert + bias pack ----------------
__global__ __launch_bounds__(256) void convert_pack(
    const float* __restrict__ Wq, const float* __restrict__ Wk,
    const float* __restrict__ Wv, const float* __restrict__ Wo,
    const float* __restrict__ W1, const float* __restrict__ W2,
    const float* __restrict__ bq, const float* __restrict__ bk,
    const float* __restrict__ bv, bf16_t* __restrict__ wbf,
    float* __restrict__ bqkv) {
  const int y = blockIdx.y;
  if (y == 6) {
    int i = blockIdx.x * 256 + threadIdx.x;
    if (i < 3072)
      bqkv[i] = i < 1024 ? bq[i] : (i < 2048 ? bk[i - 1024] : bv[i - 2048]);
    return;
  }
  const float* src; bf16_t* dst; int n;
  switch (y) {
    case 0: src = Wq; dst = wbf;           n = MEG;     break;
    case 1: src = Wk; dst = wbf + MEG;     n = MEG;     break;
    case 2: src = Wv; dst = wbf + 2*MEG;   n = MEG;     break;
    case 3: src = Wo; dst = wbf + 3*MEG;   n = MEG;     break;
    case 4: src = W1; dst = wbf + 4*MEG;   n = 4*MEG;   break;
    default: src = W2; dst = wbf + 8*MEG;  n = 4*MEG;   break;
  }
  int idx = (blockIdx.x * 256 + threadIdx.x) * 4;
  if (idx < n) {
    float4 v = *(const float4*)(src + idx);
    bf16x4 pk;
    pk.x = (__bf16)v.x; pk.y = (__bf16)v.y; pk.z = (__bf16)v.z; pk.w = (__bf16)v.w;
    *(bf16x4*)(dst + idx) = pk;
  }
}

// ---------------- adaLN: one wave per output o, all 4 batches ----------------
__global__ __launch_bounds__(256) void ada_mod(
    const float* __restrict__ cond, const float* __restrict__ Wada,
    const float* __restrict__ bada, float* __restrict__ mod) {
  const int wave = threadIdx.x >> 6, lane = threadIdx.x & 63;
  const int o = blockIdx.x * 4 + wave;      // 0..6143
  const float* wr = Wada + (size_t)o * D_;
  float a0 = 0.f, a1 = 0.f, a2 = 0.f, a3 = 0.f;
#pragma unroll
  for (int l = 0; l < 16; l++) {
    int i = l * 64 + lane;
    float w = wr[i];
    float c0 = cond[i], c1 = cond[1024 + i], c2 = cond[2048 + i], c3 = cond[3072 + i];
    a0 += w * (c0 / (1.0f + __expf(-c0)));
    a1 += w * (c1 / (1.0f + __expf(-c1)));
    a2 += w * (c2 / (1.0f + __expf(-c2)));
    a3 += w * (c3 / (1.0f + __expf(-c3)));
  }
#pragma unroll
  for (int offs = 32; offs; offs >>= 1) {
    a0 += __shfl_xor(a0, offs);
    a1 += __shfl_xor(a1, offs);
    a2 += __shfl_xor(a2, offs);
    a3 += __shfl_xor(a3, offs);
  }
  if (lane == 0) {
    float bb = bada[o];
    mod[o]          = a0 + bb;
    mod[6144 + o]   = a1 + bb;
    mod[12288 + o]  = a2 + bb;
    mod[18432 + o]  = a3 + bb;
  }
}

// ---------------- LayerNorm + modulate -> bf16 ----------------
__global__ __launch_bounds__(256) void ln_modulate(
    const float* __restrict__ X, const float* __restrict__ mod,
    bf16_t* __restrict__ H, int goff) {
  const int row = blockIdx.x;
  const int b = row >> 10;
  const int t = threadIdx.x;
  const float* xr = X + (size_t)row * D_;
  float4 xv = *(const float4*)(xr + t * 4);
  float s = xv.x + xv.y + xv.z + xv.w;
  float q = xv.x*xv.x + xv.y*xv.y + xv.z*xv.z + xv.w*xv.w;
  const int wave = t >> 6, lane = t & 63;
#pragma unroll
  for (int offs = 32; offs; offs >>= 1) {
    s += __shfl_down(s, offs);
    q += __shfl_down(q, offs);
  }
  __shared__ float sb[4][2];
  if (lane == 0) { sb[wave][0] = s; sb[wave][1] = q; }
  __syncthreads();
  float st = sb[0][0] + sb[1][0] + sb[2][0] + sb[3][0];
  float qt = sb[0][1] + sb[1][1] + sb[2][1] + sb[3][1];
  float mu = st * (1.0f / D_);
  float var = qt * (1.0f / D_) - mu * mu;
  float rstd = rsqrtf(var + 1e-6f);
  const float* mb = mod + (size_t)b * 6144 + goff;
  const int c = t * 4;
  float4 gm = *(const float4*)(mb + c);
  float4 bt = *(const float4*)(mb + 1024 + c);
  bf16x4 pk;
  pk.x = (__bf16)((xv.x - mu) * rstd * (1.0f + bt.x) + gm.x);
  pk.y = (__bf16)((xv.y - mu) * rstd * (1.0f + bt.y) + gm.y);
  pk.z = (__bf16)((xv.z - mu) * rstd * (1.0f + bt.z) + gm.z);
  pk.w = (__bf16)((xv.w - mu) * rstd * (1.0f + bt.w) + gm.w);
  *(bf16x4*)(H + (size_t)row * D_ + c) = pk;
}

// ---------------- V transpose: vT[b,h,d,s] <- qkv[b,s, 2048+h*64+d] ----------------
__global__ __launch_bounds__(256) void transpose_v(
    const bf16_t* __restrict__ qkv, bf16_t* __restrict__ vT) {
  __shared__ bf16_t tile[64][65];
  const int bh = blockIdx.y;
  const int b = bh >> 4, hh = bh & 15;
  const int s0 = blockIdx.x * 64;
  const int t = threadIdx.x;
  const int tx = t & 63, ty = t >> 6;
  const bf16_t* src = qkv + (size_t)b * S_ * 3072 + 2048 + hh * 64;
  for (int r = ty; r < 64; r += 4)
    tile[r][tx] = src[(size_t)(s0 + r) * 3072 + tx];
  __syncthreads();
  bf16_t* dst = vT + (size_t)bh * 64 * 1024;
  for (int r = ty; r < 64; r += 4)
    dst[(size_t)r * 1024 + s0 + tx] = tile[tx][r];
}

// ---------------- flash attention (v4, verified) ----------------
__global__ __launch_bounds__(512, 4) void flash_attn(
    const bf16_t* __restrict__ qkv, const bf16_t* __restrict__ vT,
    bf16_t* __restrict__ attn) {
  __shared__ __align__(16) bf16_t Ks[2][2][64 * 64];
  __shared__ __align__(16) bf16_t Vs[2][2][64 * 64];
  __shared__ __align__(16) bf16_t Ps[8][16 * 64];

  const int t = threadIdx.x;
  const int wave = t >> 6, lane = t & 63;
  const int lm = lane & 15, quad = lane >> 4;
  const int bh = blockIdx.y;
  const int b = bh >> 4, hh = bh & 15;
  const int s0 = blockIdx.x * 128;

  const bf16_t* qbase = qkv + (size_t)b * S_ * 3072 + hh * 64;
  const bf16_t* kbase = qbase + 1024;
  const bf16_t* vbase = vT + (size_t)bh * (64 * 1024);

  const int row0 = t >> 3;            // 0..63
  const int cg = (t & 7) ^ (row0 & 7);
  const int od = t * 8;               // LDS element offset

  async_copy16(qbase + (size_t)(s0 + row0) * 3072 + cg * 8, &Ks[1][0][od]);
  async_copy16(qbase + (size_t)(s0 + 64 + row0) * 3072 + cg * 8, &Ks[1][1][od]);
  async_copy16(kbase + (size_t)row0 * 3072 + cg * 8, &Ks[0][0][od]);
  async_copy16(kbase + (size_t)(64 + row0) * 3072 + cg * 8, &Ks[0][1][od]);
  async_copy16(vbase + (size_t)row0 * 1024 + cg * 8, &Vs[0][0][od]);
  async_copy16(vbase + (size_t)row0 * 1024 + 64 + cg * 8, &Vs[0][1][od]);
  __syncthreads();

  bf16x8 aq0, aq1;
  {
    const int rq = wave * 16 + lm;
    const int qh = rq >> 6, qr = rq & 63;
    const int rbq = lm & 7;
    aq0 = *(const bf16x8*)&Ks[1][qh][qr * 64 + (quad ^ rbq) * 8];
    aq1 = *(const bf16x8*)&Ks[1][qh][qr * 64 + ((4 + quad) ^ rbq) * 8];
  }
  __syncthreads();

  f32x4 accO[4] = {};
  float mrow[4], lsum[4];
#pragma unroll
  for (int r = 0; r < 4; r++) { mrow[r] = -1e30f; lsum[r] = 0.f; }

  const float SC = 0.18033688f;         // 0.125 * log2(e): exp2 domain
  const int rb = lm & 7;
  bf16_t* Pw = Ps[wave];

  for (int tt = 0; tt < 8; ++tt) {
    const int cur = tt & 1;
    if (tt < 7) {
      const int nb = cur ^ 1;
      const size_t k0n = (size_t)(tt + 1) << 7;
      async_copy16(kbase + (k0n + row0) * 3072 + cg * 8, &Ks[nb][0][od]);
      async_copy16(kbase + (k0n + 64 + row0) * 3072 + cg * 8, &Ks[nb][1][od]);
      async_copy16(vbase + (size_t)row0 * 1024 + k0n + cg * 8, &Vs[nb][0][od]);
      async_copy16(vbase + (size_t)row0 * 1024 + k0n + 64 + cg * 8, &Vs[nb][1][od]);
    }

    f32x4 accS[8];
#pragma unroll
    for (int j = 0; j < 8; j++) accS[j] = (f32x4){0.f, 0.f, 0.f, 0.f};
    __builtin_amdgcn_s_setprio(1);
#pragma unroll
    for (int hf = 0; hf < 2; hf++) {
#pragma unroll
      for (int ni = 0; ni < 4; ni++) {
        const int rk = ni * 16 + lm;
        bf16x8 b0 = *(const bf16x8*)&Ks[cur][hf][rk * 64 + ((quad ^ rb)) * 8];
        bf16x8 b1 = *(const bf16x8*)&Ks[cur][hf][rk * 64 + (((4 + quad) ^ rb)) * 8];
        f32x4 a = accS[hf * 4 + ni];
        a = __builtin_amdgcn_mfma_f32_16x16x32_bf16(aq0, b0, a, 0, 0, 0);
        a = __builtin_amdgcn_mfma_f32_16x16x32_bf16(aq1, b1, a, 0, 0, 0);
        accS[hf * 4 + ni] = a;
      }
    }
    __builtin_amdgcn_s_setprio(0);

    float mx[4];
#pragma unroll
    for (int r = 0; r < 4; r++) {
      float m0 = fmaxf(fmaxf(accS[0][r], accS[1][r]), fmaxf(accS[2][r], accS[3][r]));
      float m1 = fmaxf(fmaxf(accS[4][r], accS[5][r]), fmaxf(accS[6][r], accS[7][r]));
      float m8 = fmaxf(m0, m1);
      m8 = fmaxf(m8, __shfl_xor(m8, 1));
      m8 = fmaxf(m8, __shfl_xor(m8, 2));
      m8 = fmaxf(m8, __shfl_xor(m8, 4));
      m8 = fmaxf(m8, __shfl_xor(m8, 8));
      mx[r] = m8 * SC;
    }
    bool ok = (mx[0] - mrow[0] <= 8.0f) && (mx[1] - mrow[1] <= 8.0f) &&
              (mx[2] - mrow[2] <= 8.0f) && (mx[3] - mrow[3] <= 8.0f);
    if (!__all(ok)) {
#pragma unroll
      for (int r = 0; r < 4; r++) {
        float mnew = fmaxf(mrow[r], mx[r]);
        float al = exp2f(mrow[r] - mnew);
        mrow[r] = mnew;
        lsum[r] *= al;
#pragma unroll
        for (int di = 0; di < 4; di++) accO[di][r] *= al;
      }
    }
#pragma unroll
    for (int r = 0; r < 4; r++) {
      float sum = 0.f;
#pragma unroll
      for (int j = 0; j < 8; j++) {
        float p = exp2f(accS[j][r] * SC - mrow[r]);
        accS[j][r] = p;
        sum += p;
      }
      lsum[r] += sum;
    }

#pragma unroll
    for (int hf = 0; hf < 2; hf++) {
#pragma unroll
      for (int jj = 0; jj < 4; jj++)
#pragma unroll
        for (int r = 0; r < 4; r++) {
          int prow = quad * 4 + r;
          int c = jj * 16 + lm;
          Pw[prow * 64 + (((c >> 3) ^ (prow & 7)) << 3) + (c & 7)] =
              (__bf16)accS[hf * 4 + jj][r];
        }
      __builtin_amdgcn_s_setprio(1);
#pragma unroll
      for (int loc = 0; loc < 2; loc++) {
        bf16x8 ap = *(const bf16x8*)&Pw[lm * 64 + (((loc * 4 + quad) ^ rb)) * 8];
#pragma unroll
        for (int di = 0; di < 4; di++) {
          const int rv = di * 16 + lm;
          bf16x8 vv = *(const bf16x8*)&Vs[cur][hf]
              [rv * 64 + (((loc * 4 + quad) ^ rb)) * 8];
          accO[di] = __builtin_amdgcn_mfma_f32_16x16x32_bf16(ap, vv, accO[di], 0, 0, 0);
        }
      }
      __builtin_amdgcn_s_setprio(0);
    }
    __syncthreads();
  }

#pragma unroll
  for (int r = 0; r < 4; r++) {
    float sv = lsum[r];
    sv += __shfl_xor(sv, 1);
    sv += __shfl_xor(sv, 2);
    sv += __shfl_xor(sv, 4);
    sv += __shfl_xor(sv, 8);
    lsum[r] = sv;
  }

#pragma unroll
  for (int r = 0; r < 4; r++) {
    float inv = 1.0f / lsum[r];
    int prow = quad * 4 + r;
#pragma unroll
    for (int di = 0; di < 4; di++) {
      int col = di * 16 + lm;
      int cph = (col >> 3) ^ (prow & 7);
      Pw[prow * 64 + cph * 8 + (col & 7)] = (__bf16)(accO[di][r] * inv);
    }
  }
  bf16_t* abase = attn + (size_t)b * S_ * 1024 +
                  (size_t)(s0 + wave * 16) * 1024 + hh * 64;
#pragma unroll
  for (int it = 0; it < 2; it++) {
    int slot = it * 64 + lane;
    int orow = slot >> 3;
    int gc = slot & 7;
    int cph = gc ^ (orow & 7);
    bf16x8 val = *(const bf16x8*)&Pw[orow * 64 + cph * 8];
    *(bf16x8*)(abase + (size_t)orow * 1024 + gc * 8) = val;
  }
}

// ---------------- NEW: big-tile GEMM (v6-verified schedule, 256x256 geometry) -
// BM=256, BN=256, BK=64, 512 threads, 8 waves as 2M x 4N, per-wave 128x64
// (acc[8][4]). 64 MFMA per 24 ds_read_b128 per wave per K-tile. Monolithic
// v6 schedule: one vmcnt(0)+barrier per K-tile, stage-all (8 units), then
// read + MFMA. Double-buffered LDS = 128KB -> 1 block/CU (512 thr).
// Zero-conflict XOR swizzle identical to the verified v6/flash tiles:
//   LDS slot s of row r holds global chunk s^(r&7); reader slot (ks*4+quad)^(lm&7).
// XCD-bijective swizzle (grid blocks %8==0). M,N mult of 256; K mult of 64.
// EPI: 0 = (+bias) -> bf16 ; 3 = gelu(acc+bias) -> bf16
template <int EPI>
__global__ __launch_bounds__(512) void gemm_bt_big(
    const bf16_t* __restrict__ A, int lda,
    const bf16_t* __restrict__ B, int ldb,
    bf16_t* __restrict__ C, int ldc,
    int M, int N, int K,
    const float* __restrict__ bias) {
  __shared__ __align__(16) bf16_t As[2][4][64 * 64];   // 64KB
  __shared__ __align__(16) bf16_t Bs[2][4][64 * 64];   // 64KB

  const int gx = gridDim.x;
  int d = blockIdx.x + gx * blockIdx.y;
  const int cpx = (gx * gridDim.y) >> 3;
  int wg = (d & 7) * cpx + (d >> 3);
  const int by = wg / gx;     // M-tile
  const int bx = wg % gx;     // N-tile

  const int t = threadIdx.x;
  const int wave = t >> 6;
  const int lane = t & 63;
  const int lm = lane & 15;
  const int quad = lane >> 4;
  const int wr = wave >> 2;   // 0..1: M half (128 rows)
  const int wc = wave & 3;    // 0..3: N quarter (64 cols)

  const int m0 = by * 256;
  const int n0 = bx * 256;

  f32x4 acc[8][4] = {};

  // staging: unit = 64 rows x 64 cols (8KB = 512 lanes x 16B);
  // thread t -> row t>>3, LDS slot t&7 holds global chunk (t&7)^(row&7)
  const int srow = t >> 3;
  const int scg = (t & 7) ^ (srow & 7);
  const int sod = t * 8;
  const bf16_t* Ag = A + (size_t)(m0 + srow) * lda + scg * 8;
  const bf16_t* Bg = B + (size_t)(n0 + srow) * ldb + scg * 8;
  const size_t aStep = (size_t)64 * lda;
  const size_t bStep = (size_t)64 * ldb;

#define STAGE8(buf, ko)                                        \
  async_copy16(Ag + (ko), &As[buf][0][sod]);                   \
  async_copy16(Ag + aStep + (ko), &As[buf][1][sod]);           \
  async_copy16(Ag + 2 * aStep + (ko), &As[buf][2][sod]);       \
  async_copy16(Ag + 3 * aStep + (ko), &As[buf][3][sod]);       \
  async_copy16(Bg + (ko), &Bs[buf][0][sod]);                   \
  async_copy16(Bg + bStep + (ko), &Bs[buf][1][sod]);           \
  async_copy16(Bg + 2 * bStep + (ko), &Bs[buf][2][sod]);       \
  async_copy16(Bg + 3 * bStep + (ko), &Bs[buf][3][sod]);

  const int niter = K >> 6;
  STAGE8(0, 0);

  const int rbx = lm & 7;
  const int sl0 = (quad ^ rbx) * 8;          // ks=0 slot offset
  const int sl1 = ((4 + quad) ^ rbx) * 8;    // ks=1 slot offset
  const int abase = wr * 8192 + lm * 64;     // + (mi>>2)*4096 + (mi&3)*1024
  const int bbase = wc * 4096 + lm * 64;     // + ni*1024

  int cur = 0;
  for (int it = 0; it < niter; ++it) {
    asm volatile("s_waitcnt vmcnt(0)\n\ts_barrier" ::: "memory");
    if (it + 1 < niter) {
      const int ko = (it + 1) << 6;
      const int nb = cur ^ 1;
      STAGE8(nb, ko);
    }
    const bf16_t* Ac = &As[cur][0][0];
    const bf16_t* Bc = &Bs[cur][0][0];

    bf16x8 bfr[4][2];
#pragma unroll
    for (int ni = 0; ni < 4; ni++) {
      bfr[ni][0] = *(const bf16x8*)&Bc[bbase + ni * 1024 + sl0];
      bfr[ni][1] = *(const bf16x8*)&Bc[bbase + ni * 1024 + sl1];
    }
    __builtin_amdgcn_s_setprio(1);
#pragma unroll
    for (int mi = 0; mi < 8; mi++) {
      const int aoff = abase + (mi >> 2) * 4096 + (mi & 3) * 1024;
      bf16x8 a0 = *(const bf16x8*)&Ac[aoff + sl0];
      bf16x8 a1 = *(const bf16x8*)&Ac[aoff + sl1];
#pragma unroll
      for (int ni = 0; ni < 4; ni++) {
        acc[mi][ni] = __builtin_amdgcn_mfma_f32_16x16x32_bf16(
            a0, bfr[ni][0], acc[mi][ni], 0, 0, 0);
        acc[mi][ni] = __builtin_amdgcn_mfma_f32_16x16x32_bf16(
            a1, bfr[ni][1], acc[mi][ni], 0, 0, 0);
      }
    }
    __builtin_amdgcn_s_setprio(0);
    cur ^= 1;
  }
#undef STAGE8

#pragma unroll
  for (int mi = 0; mi < 8; mi++) {
#pragma unroll
    for (int ni = 0; ni < 4; ni++) {
#pragma unroll
      for (int r = 0; r < 4; r++) {
        int row = m0 + wr * 128 + mi * 16 + quad * 4 + r;
        int col = n0 + wc * 64 + ni * 16 + lm;
        float v = acc[mi][ni][r];
        size_t idx = (size_t)row * ldc + col;
        if (EPI == 0) {
          if (bias) v += bias[col];
          C[idx] = (__bf16)v;
        } else if (EPI == 3) {
          v += bias[col];
          float u = 1.5957691216f * (v + 0.044715f * v * v * v);
          float g = v / (1.0f + __expf(-u));
          C[idx] = (__bf16)g;
        }
      }
    }
  }
}

// ---------------- C = A * B^T GEMM (v7, verified): 256x128, phase-split ------
// 512 threads, BM=256 BN=128 BK=64, 8 waves (4M x 2N), per-wave 64x64.
// Ring-of-3 LDS (144KB), staged 2 K-tiles ahead, counted vmcnt(6).
// Each K-tile split into 2 phases of 16 MFMA (double-barrier rhythm).
// EPI: 0 = (+bias) -> bf16 ; 1 = identity -> f32 ; 3 = gelu(acc+bias) -> bf16
template <int EPI>
__global__ __launch_bounds__(512) void gemm_bt(
    const bf16_t* __restrict__ A, int lda, long long sAz,
    const bf16_t* __restrict__ B, int ldb, long long sBz,
    void* __restrict__ Cv, int ldc, long long sCz,
    int M, int N, int K,
    const float* __restrict__ bias,
    float scale) {
  __shared__ __align__(16) bf16_t As[3][256 * 64];   // 96KB
  __shared__ __align__(16) bf16_t Bs[3][128 * 64];   // 48KB

  const int z = blockIdx.z;
  A += (size_t)z * sAz;
  B += (size_t)z * sBz;

  const int gx = gridDim.x;
  int d = blockIdx.x + gx * blockIdx.y;
  {
    const int cpx = (gx * gridDim.y) >> 3;
    int wg = (d & 7) * cpx + (d >> 3);
    const int by = wg / gx;     // M-tile
    const int bx = wg % gx;     // N-tile

    const int t = threadIdx.x;
    const int wave = t >> 6;
    const int lane = t & 63;
    const int lm = lane & 15;
    const int quad = lane >> 4;
    const int wr = wave >> 1;   // 0..3: M sub-block
    const int wc = wave & 1;    // 0..1: N sub-block

    const int m0 = by * 256;
    const int n0 = bx * 128;

    f32x4 acc[4][4] = {};

    const int srow = t >> 3;                    // 0..63
    const int scg = (t & 7) ^ (srow & 7);
    const int sod = t * 8;                      // LDS elem offset in unit
    const bf16_t* Ag = A + (size_t)(m0 + srow) * lda + scg * 8;
    const bf16_t* Bg = B + (size_t)(n0 + srow) * ldb + scg * 8;
    const size_t a64 = (size_t)64 * lda, a128 = (size_t)128 * lda,
                 a192 = (size_t)192 * lda, b64 = (size_t)64 * ldb;

#define STAGE6(buf, ko)                                      \
  async_copy16(Ag + (ko), &As[buf][sod]);                    \
  async_copy16(Ag + a64 + (ko), &As[buf][4096 + sod]);       \
  async_copy16(Ag + a128 + (ko), &As[buf][8192 + sod]);      \
  async_copy16(Ag + a192 + (ko), &As[buf][12288 + sod]);     \
  async_copy16(Bg + (ko), &Bs[buf][sod]);                    \
  async_copy16(Bg + b64 + (ko), &Bs[buf][4096 + sod]);

    const int niter = K >> 6;
    STAGE6(0, 0);
    STAGE6(1, 64);

    const int rbx = lm & 7;
    const int sl0 = (quad ^ rbx) * 8;          // ks=0 slot offset
    const int sl1 = ((4 + quad) ^ rbx) * 8;    // ks=1 slot offset
    const int arow = wr * 4096 + lm * 64;      // + mi*1024
    const int brow = wc * 4096 + lm * 64;

    int cur = 0;
    for (int it = 0; it < niter; ++it) {
      if (it + 1 < niter) {
        asm volatile("s_waitcnt vmcnt(6)" ::: "memory");
      } else {
        asm volatile("s_waitcnt vmcnt(0)" ::: "memory");
      }
      __builtin_amdgcn_s_barrier();            // buf[cur] ready for all waves
      const int nb = (cur >= 1) ? cur - 1 : 2; // ring slot for tile it+2
      const int ko = (it + 2) << 6;
      const bool st = (it + 2 < niter);

      // ---------------- phase A ----------------
      bf16x8 af0[2], af1[2], bfr[4][2];
      af0[0] = *(const bf16x8*)&As[cur][arow + sl0];
      af0[1] = *(const bf16x8*)&As[cur][arow + sl1];
      af1[0] = *(const bf16x8*)&As[cur][arow + 1024 + sl0];
      af1[1] = *(const bf16x8*)&As[cur][arow + 1024 + sl1];
#pragma unroll
      for (int i = 0; i < 4; i++) {
        bfr[i][0] = *(const bf16x8*)&Bs[cur][brow + i * 1024 + sl0];
        bfr[i][1] = *(const bf16x8*)&Bs[cur][brow + i * 1024 + sl1];
      }
      if (st) {
        async_copy16(Ag + ko, &As[nb][sod]);
        async_copy16(Ag + a64 + ko, &As[nb][4096 + sod]);
        async_copy16(Ag + a128 + ko, &As[nb][8192 + sod]);
      }
      __builtin_amdgcn_s_barrier();
      __builtin_amdgcn_s_setprio(1);
#pragma unroll
      for (int ks = 0; ks < 2; ks++)
#pragma unroll
        for (int ni = 0; ni < 4; ni++) {
          acc[0][ni] = __builtin_amdgcn_mfma_f32_16x16x32_bf16(
              af0[ks], bfr[ni][ks], acc[0][ni], 0, 0, 0);
          acc[1][ni] = __builtin_amdgcn_mfma_f32_16x16x32_bf16(
              af1[ks], bfr[ni][ks], acc[1][ni], 0, 0, 0);
        }
      __builtin_amdgcn_s_setprio(0);
      __builtin_amdgcn_s_barrier();

      // ---------------- phase B ----------------
      bf16x8 af2[2], af3[2];
      af2[0] = *(const bf16x8*)&As[cur][arow + 2048 + sl0];
      af2[1] = *(const bf16x8*)&As[cur][arow + 2048 + sl1];
      af3[0] = *(const bf16x8*)&As[cur][arow + 3072 + sl0];
      af3[1] = *(const bf16x8*)&As[cur][arow + 3072 + sl1];
      if (st) {
        async_copy16(Ag + a192 + ko, &As[nb][12288 + sod]);
        async_copy16(Bg + ko, &Bs[nb][sod]);
        async_copy16(Bg + b64 + ko, &Bs[nb][4096 + sod]);
      }
      __builtin_amdgcn_s_barrier();
      __builtin_amdgcn_s_setprio(1);
#pragma unroll
      for (int ks = 0; ks < 2; ks++)
#pragma unroll
        for (int ni = 0; ni < 4; ni++) {
          acc[2][ni] = __builtin_amdgcn_mfma_f32_16x16x32_bf16(
              af2[ks], bfr[ni][ks], acc[2][ni], 0, 0, 0);
          acc[3][ni] = __builtin_amdgcn_mfma_f32_16x16x32_bf16(
              af3[ks], bfr[ni][ks], acc[3][ni], 0, 0, 0);
        }
      __builtin_amdgcn_s_setprio(0);
      cur = (cur == 2) ? 0 : cur + 1;
    }
#undef STAGE6

    const size_t cz = (size_t)z * sCz;
#pragma unroll
    for (int mi = 0; mi < 4; mi++) {
#pragma unroll
      for (int ni = 0; ni < 4; ni++) {
#pragma unroll
        for (int r = 0; r < 4; r++) {
          int row = m0 + wr * 64 + mi * 16 + quad * 4 + r;
          int col = n0 + wc * 64 + ni * 16 + lm;
          float v = acc[mi][ni][r];
          size_t idx = cz + (size_t)row * ldc + col;
          if (EPI == 1) {
            ((float*)Cv)[idx] = v * scale;
          } else if (EPI == 0) {
            if (bias) v += bias[col];
            ((bf16_t*)Cv)[idx] = (__bf16)v;
          } else if (EPI == 3) {
            v += bias[col];
            float u = 1.5957691216f * (v + 0.044715f * v * v * v);
            float g = v / (1.0f + __expf(-u));
            ((bf16_t*)Cv)[idx] = (__bf16)g;
          }
        }
      }
    }
  }
}

// ---------------- Wo split-K reduce + residual + LN2 + modulate ----------------
__global__ __launch_bounds__(256) void reduce_ln(
    const float* __restrict__ part, const float* __restrict__ x,
    const float* __restrict__ bo, const float* __restrict__ mod,
    float* __restrict__ x1, bf16_t* __restrict__ h) {
  const int row = blockIdx.x;
  const int b = row >> 10;
  const int t = threadIdx.x;
  const int c = t * 4;
  const size_t idx = (size_t)row * 1024 + c;
  float4 p0 = *(const float4*)(part + idx);
  float4 p1 = *(const float4*)(part + 4194304 + idx);
  float4 bb = *(const float4*)(bo + c);
  float4 al = *(const float4*)(mod + (size_t)b * 6144 + 2048 + c);
  float4 xs = *(const float4*)(x + idx);
  float4 xv;
  xv.x = xs.x + al.x * (p0.x + p1.x + bb.x);
  xv.y = xs.y + al.y * (p0.y + p1.y + bb.y);
  xv.z = xs.z + al.z * (p0.z + p1.z + bb.z);
  xv.w = xs.w + al.w * (p0.w + p1.w + bb.w);
  *(float4*)(x1 + idx) = xv;

  float s = xv.x + xv.y + xv.z + xv.w;
  float q = xv.x*xv.x + xv.y*xv.y + xv.z*xv.z + xv.w*xv.w;
  const int wave = t >> 6, lane = t & 63;
#pragma unroll
  for (int offs = 32; offs; offs >>= 1) {
    s += __shfl_down(s, offs);
    q += __shfl_down(q, offs);
  }
  __shared__ float sb[4][2];
  if (lane == 0) { sb[wave][0] = s; sb[wave][1] = q; }
  __syncthreads();
  float st = sb[0][0] + sb[1][0] + sb[2][0] + sb[3][0];
  float qt = sb[0][1] + sb[1][1] + sb[2][1] + sb[3][1];
  float mu = st * (1.0f / D_);
  float var = qt * (1.0f / D_) - mu * mu;
  float rstd = rsqrtf(var + 1e-6f);
  const float* mb = mod + (size_t)b * 6144 + 3072;
  float4 gm = *(const float4*)(mb + c);
  float4 bt = *(const float4*)(mb + 1024 + c);
  bf16x4 pk;
  pk.x = (__bf16)((xv.x - mu) * rstd * (1.0f + bt.x) + gm.x);
  pk.y = (__bf16)((xv.y - mu) * rstd * (1.0f + bt.y) + gm.y);
  pk.z = (__bf16)((xv.z - mu) * rstd * (1.0f + bt.z) + gm.z);
  pk.w = (__bf16)((xv.w - mu) * rstd * (1.0f + bt.w) + gm.w);
  *(bf16x4*)(h + idx) = pk;
}

// ---------------- W2 split-K(2) reduction + epilogue ----------------
__global__ __launch_bounds__(256) void reduce_w2(
    const float* __restrict__ part, const float* __restrict__ x1,
    const float* __restrict__ b2, const float* __restrict__ mod,
    float* __restrict__ out) {
  const int idx = (blockIdx.x * 256 + threadIdx.x) * 4;
  const int col = idx & 1023;
  const int row = idx >> 10;
  const int b = row >> 10;
  float4 s0 = *(const float4*)(part + idx);
  float4 s1 = *(const float4*)(part + 4194304 + idx);
  float4 bb = *(const float4*)(b2 + col);
  float4 al = *(const float4*)(mod + (size_t)b * 6144 + 5120 + col);
  float4 rs = *(const float4*)(x1 + idx);
  float4 o;
  o.x = rs.x + al.x * (s0.x + s1.x + bb.x);
  o.y = rs.y + al.y * (s0.y + s1.y + bb.y);
  o.z = rs.z + al.z * (s0.z + s1.z + bb.z);
  o.w = rs.w + al.w * (s0.w + s1.w + bb.w);
  *(float4*)(out + idx) = o;
}

extern "C" void kernel_launch(void* const* d_in, const int* in_sizes, int n_in,
                              void* d_out, int out_size, void* d_ws, size_t ws_size,
                              hipStream_t stream) {
  (void)in_sizes; (void)n_in; (void)out_size; (void)ws_size;
  const float* x    = (const float*)d_in[0];
  const float* cond = (const float*)d_in[1];
  const float* Wq   = (const float*)d_in[2];
  const float* bq   = (const float*)d_in[3];
  const float* Wk   = (const float*)d_in[4];
  const float* bk   = (const float*)d_in[5];
  const float* Wv   = (const float*)d_in[6];
  const float* bv   = (const float*)d_in[7];
  const float* Wo   = (const float*)d_in[8];
  const float* bo   = (const float*)d_in[9];
  const float* W1   = (const float*)d_in[10];
  const float* b1   = (const float*)d_in[11];
  const float* W2   = (const float*)d_in[12];
  const float* b2   = (const float*)d_in[13];
  const float* Wada = (const float*)d_in[14];
  const float* bada = (const float*)d_in[15];

  uint8_t* ws = (uint8_t*)d_ws;
  bf16_t* wbf   = (bf16_t*)(ws + OFF_WBF);
  float*  bqkv  = (float*)(ws + OFF_BQKV);
  float*  mod   = (float*)(ws + OFF_MOD);
  bf16_t* h     = (bf16_t*)(ws + OFF_H);
  bf16_t* qkv   = (bf16_t*)(ws + OFF_QKV);
  bf16_t* vT    = (bf16_t*)(ws + OFF_VT);
  bf16_t* attn  = (bf16_t*)(ws + OFF_ATTN);
  float*  x1    = (float*)(ws + OFF_X1);
  float*  part  = (float*)(ws + OFF_PART);
  bf16_t* mlph  = (bf16_t*)(ws + OFF_MLPH);
  float* out = (float*)d_out;

  convert_pack<<<dim3(4096, 7, 1), 256, 0, stream>>>(Wq, Wk, Wv, Wo, W1, W2,
                                                     bq, bk, bv, wbf, bqkv);
  ada_mod<<<1536, 256, 0, stream>>>(cond, Wada, bada, mod);
  ln_modulate<<<4096, 256, 0, stream>>>(x, mod, h, 0);
  // qkv = h @ [Wq;Wk;Wv]^T + bias   (M=4096, N=3072, K=1024) grid 12x16=192
  gemm_bt_big<0><<<dim3(12, 16, 1), 512, 0, stream>>>(
      h, 1024, wbf, 1024, qkv, 3072, 4096, 3072, 1024, bqkv);
  transpose_v<<<dim3(16, 64, 1), 256, 0, stream>>>(qkv, vT);
  flash_attn<<<dim3(8, 64, 1), 512, 0, stream>>>(qkv, vT, attn);

  // Wo split-K=2: part[z] = attn[:, z*512:] @ Wo[:, z*512:]^T  grid 8x16x2
  gemm_bt<1><<<dim3(8, 16, 2), 512, 0, stream>>>(
      attn, 1024, 512, wbf + (size_t)3 * MEG, 1024, 512, part, 1024, 4194304,
      4096, 1024, 512, nullptr, 1.f);
  // x1 = x + alpha1*(sum part + bo); h = modulate(ln(x1), beta2, gama2)
  reduce_ln<<<4096, 256, 0, stream>>>(part, x, bo, mod, x1, h);

  // mlph = gelu(h @ W1^T + b1)   (M=4096, N=4096, K=1024) grid 16x16=256
  gemm_bt_big<3><<<dim3(16, 16, 1), 512, 0, stream>>>(
      h, 1024, wbf + (size_t)4 * MEG, 1024, mlph, 4096, 4096, 4096, 1024, b1);
  // W2 split-K=2  (M=4096, N=1024, K=2048 per z) grid 8x16x2
  gemm_bt<1><<<dim3(8, 16, 2), 512, 0, stream>>>(
      mlph, 4096, 2048, wbf + (size_t)8 * MEG, 4096, 2048, part, 1024, 4194304,
      4096, 1024, 2048, nullptr, 1.f);
  reduce_w2<<<4096, 256, 0, stream>>>(part, x1, b2, mod, out);
}

// Round 9
// 378.250 us; speedup vs baseline: 1.0905x; 1.0085x over previous
//
#include <hip/hip_runtime.h>
#include <cstdint>

typedef __bf16 bf16_t;
typedef __bf16 bf16x4 __attribute__((ext_vector_type(4)));
typedef __bf16 bf16x8 __attribute__((ext_vector_type(8)));
typedef float f32x4 __attribute__((ext_vector_type(4)));

#define B_ 4
#define S_ 1024
#define D_ 1024
#define HID_ 4096
#define MEG (1u << 20)

// ---------------- workspace layout (bytes) ----------------
static const size_t OFF_WBF  = 0;                 // 12M bf16 (Wq,Wk,Wv,Wo,W1,W2)
static const size_t OFF_BQKV = 25165824;          // 3072 f32
static const size_t OFF_MOD  = 25178112;          // 4*6144 f32
static const size_t OFF_H    = 25276416;          // 4096*1024 bf16
static const size_t OFF_QKV  = 33665024;          // 4096*3072 bf16
static const size_t OFF_VT   = 58830848;          // 4*16*64*1024 bf16
static const size_t OFF_ATTN = 67219456;          // 4096*1024 bf16
static const size_t OFF_X1   = 75608064;          // 4096*1024 f32
static const size_t OFF_PART = 92385280;          // 2 * 4096*1024 f32 (split-K partials)
static const size_t OFF_MLPH = 159494144;         // 4096*4096 bf16 = 32MB

// ---------------- async global->LDS (16B/lane) ----------------
__device__ __forceinline__ void async_copy16(const bf16_t* g, bf16_t* l) {
  __builtin_amdgcn_global_load_lds(
      (__attribute__((address_space(1))) void*)(g),
      (__attribute__((address_space(3))) void*)(l), 16, 0, 0);
}

// ---------------- weight convert + bias pack ----------------
__global__ __launch_bounds__(256) void convert_pack(
    const float* __restrict__ Wq, const float* __restrict__ Wk,
    const float* __restrict__ Wv, const float* __restrict__ Wo,
    const float* __restrict__ W1, const float* __restrict__ W2,
    const float* __restrict__ bq, const float* __restrict__ bk,
    const float* __restrict__ bv, bf16_t* __restrict__ wbf,
    float* __restrict__ bqkv) {
  const int y = blockIdx.y;
  if (y == 6) {
    int i = blockIdx.x * 256 + threadIdx.x;
    if (i < 3072)
      bqkv[i] = i < 1024 ? bq[i] : (i < 2048 ? bk[i - 1024] : bv[i - 2048]);
    return;
  }
  const float* src; bf16_t* dst; int n;
  switch (y) {
    case 0: src = Wq; dst = wbf;           n = MEG;     break;
    case 1: src = Wk; dst = wbf + MEG;     n = MEG;     break;
    case 2: src = Wv; dst = wbf + 2*MEG;   n = MEG;     break;
    case 3: src = Wo; dst = wbf + 3*MEG;   n = MEG;     break;
    case 4: src = W1; dst = wbf + 4*MEG;   n = 4*MEG;   break;
    default: src = W2; dst = wbf + 8*MEG;  n = 4*MEG;   break;
  }
  int idx = (blockIdx.x * 256 + threadIdx.x) * 4;
  if (idx < n) {
    float4 v = *(const float4*)(src + idx);
    bf16x4 pk;
    pk.x = (__bf16)v.x; pk.y = (__bf16)v.y; pk.z = (__bf16)v.z; pk.w = (__bf16)v.w;
    *(bf16x4*)(dst + idx) = pk;
  }
}

// ---------------- adaLN: one wave per output o, all 4 batches ----------------
__global__ __launch_bounds__(256) void ada_mod(
    const float* __restrict__ cond, const float* __restrict__ Wada,
    const float* __restrict__ bada, float* __restrict__ mod) {
  const int wave = threadIdx.x >> 6, lane = threadIdx.x & 63;
  const int o = blockIdx.x * 4 + wave;      // 0..6143
  const float* wr = Wada + (size_t)o * D_;
  float a0 = 0.f, a1 = 0.f, a2 = 0.f, a3 = 0.f;
#pragma unroll
  for (int l = 0; l < 16; l++) {
    int i = l * 64 + lane;
    float w = wr[i];
    float c0 = cond[i], c1 = cond[1024 + i], c2 = cond[2048 + i], c3 = cond[3072 + i];
    a0 += w * (c0 / (1.0f + __expf(-c0)));
    a1 += w * (c1 / (1.0f + __expf(-c1)));
    a2 += w * (c2 / (1.0f + __expf(-c2)));
    a3 += w * (c3 / (1.0f + __expf(-c3)));
  }
#pragma unroll
  for (int offs = 32; offs; offs >>= 1) {
    a0 += __shfl_xor(a0, offs);
    a1 += __shfl_xor(a1, offs);
    a2 += __shfl_xor(a2, offs);
    a3 += __shfl_xor(a3, offs);
  }
  if (lane == 0) {
    float bb = bada[o];
    mod[o]          = a0 + bb;
    mod[6144 + o]   = a1 + bb;
    mod[12288 + o]  = a2 + bb;
    mod[18432 + o]  = a3 + bb;
  }
}

// ---------------- LayerNorm + modulate -> bf16 ----------------
__global__ __launch_bounds__(256) void ln_modulate(
    const float* __restrict__ X, const float* __restrict__ mod,
    bf16_t* __restrict__ H, int goff) {
  const int row = blockIdx.x;
  const int b = row >> 10;
  const int t = threadIdx.x;
  const float* xr = X + (size_t)row * D_;
  float4 xv = *(const float4*)(xr + t * 4);
  float s = xv.x + xv.y + xv.z + xv.w;
  float q = xv.x*xv.x + xv.y*xv.y + xv.z*xv.z + xv.w*xv.w;
  const int wave = t >> 6, lane = t & 63;
#pragma unroll
  for (int offs = 32; offs; offs >>= 1) {
    s += __shfl_down(s, offs);
    q += __shfl_down(q, offs);
  }
  __shared__ float sb[4][2];
  if (lane == 0) { sb[wave][0] = s; sb[wave][1] = q; }
  __syncthreads();
  float st = sb[0][0] + sb[1][0] + sb[2][0] + sb[3][0];
  float qt = sb[0][1] + sb[1][1] + sb[2][1] + sb[3][1];
  float mu = st * (1.0f / D_);
  float var = qt * (1.0f / D_) - mu * mu;
  float rstd = rsqrtf(var + 1e-6f);
  const float* mb = mod + (size_t)b * 6144 + goff;
  const int c = t * 4;
  float4 gm = *(const float4*)(mb + c);
  float4 bt = *(const float4*)(mb + 1024 + c);
  bf16x4 pk;
  pk.x = (__bf16)((xv.x - mu) * rstd * (1.0f + bt.x) + gm.x);
  pk.y = (__bf16)((xv.y - mu) * rstd * (1.0f + bt.y) + gm.y);
  pk.z = (__bf16)((xv.z - mu) * rstd * (1.0f + bt.z) + gm.z);
  pk.w = (__bf16)((xv.w - mu) * rstd * (1.0f + bt.w) + gm.w);
  *(bf16x4*)(H + (size_t)row * D_ + c) = pk;
}

// ---------------- V transpose: vT[b,h,d,s] <- qkv[b,s, 2048+h*64+d] ----------------
__global__ __launch_bounds__(256) void transpose_v(
    const bf16_t* __restrict__ qkv, bf16_t* __restrict__ vT) {
  __shared__ bf16_t tile[64][65];
  const int bh = blockIdx.y;
  const int b = bh >> 4, hh = bh & 15;
  const int s0 = blockIdx.x * 64;
  const int t = threadIdx.x;
  const int tx = t & 63, ty = t >> 6;
  const bf16_t* src = qkv + (size_t)b * S_ * 3072 + 2048 + hh * 64;
  for (int r = ty; r < 64; r += 4)
    tile[r][tx] = src[(size_t)(s0 + r) * 3072 + tx];
  __syncthreads();
  bf16_t* dst = vT + (size_t)bh * 64 * 1024;
  for (int r = ty; r < 64; r += 4)
    dst[(size_t)r * 1024 + s0 + tx] = tile[tx][r];
}

// ---------------- flash attention (v4, verified) ----------------
__global__ __launch_bounds__(512, 4) void flash_attn(
    const bf16_t* __restrict__ qkv, const bf16_t* __restrict__ vT,
    bf16_t* __restrict__ attn) {
  __shared__ __align__(16) bf16_t Ks[2][2][64 * 64];
  __shared__ __align__(16) bf16_t Vs[2][2][64 * 64];
  __shared__ __align__(16) bf16_t Ps[8][16 * 64];

  const int t = threadIdx.x;
  const int wave = t >> 6, lane = t & 63;
  const int lm = lane & 15, quad = lane >> 4;
  const int bh = blockIdx.y;
  const int b = bh >> 4, hh = bh & 15;
  const int s0 = blockIdx.x * 128;

  const bf16_t* qbase = qkv + (size_t)b * S_ * 3072 + hh * 64;
  const bf16_t* kbase = qbase + 1024;
  const bf16_t* vbase = vT + (size_t)bh * (64 * 1024);

  const int row0 = t >> 3;            // 0..63
  const int cg = (t & 7) ^ (row0 & 7);
  const int od = t * 8;               // LDS element offset

  async_copy16(qbase + (size_t)(s0 + row0) * 3072 + cg * 8, &Ks[1][0][od]);
  async_copy16(qbase + (size_t)(s0 + 64 + row0) * 3072 + cg * 8, &Ks[1][1][od]);
  async_copy16(kbase + (size_t)row0 * 3072 + cg * 8, &Ks[0][0][od]);
  async_copy16(kbase + (size_t)(64 + row0) * 3072 + cg * 8, &Ks[0][1][od]);
  async_copy16(vbase + (size_t)row0 * 1024 + cg * 8, &Vs[0][0][od]);
  async_copy16(vbase + (size_t)row0 * 1024 + 64 + cg * 8, &Vs[0][1][od]);
  __syncthreads();

  bf16x8 aq0, aq1;
  {
    const int rq = wave * 16 + lm;
    const int qh = rq >> 6, qr = rq & 63;
    const int rbq = lm & 7;
    aq0 = *(const bf16x8*)&Ks[1][qh][qr * 64 + (quad ^ rbq) * 8];
    aq1 = *(const bf16x8*)&Ks[1][qh][qr * 64 + ((4 + quad) ^ rbq) * 8];
  }
  __syncthreads();

  f32x4 accO[4] = {};
  float mrow[4], lsum[4];
#pragma unroll
  for (int r = 0; r < 4; r++) { mrow[r] = -1e30f; lsum[r] = 0.f; }

  const float SC = 0.18033688f;         // 0.125 * log2(e): exp2 domain
  const int rb = lm & 7;
  bf16_t* Pw = Ps[wave];

  for (int tt = 0; tt < 8; ++tt) {
    const int cur = tt & 1;
    if (tt < 7) {
      const int nb = cur ^ 1;
      const size_t k0n = (size_t)(tt + 1) << 7;
      async_copy16(kbase + (k0n + row0) * 3072 + cg * 8, &Ks[nb][0][od]);
      async_copy16(kbase + (k0n + 64 + row0) * 3072 + cg * 8, &Ks[nb][1][od]);
      async_copy16(vbase + (size_t)row0 * 1024 + k0n + cg * 8, &Vs[nb][0][od]);
      async_copy16(vbase + (size_t)row0 * 1024 + k0n + 64 + cg * 8, &Vs[nb][1][od]);
    }

    f32x4 accS[8];
#pragma unroll
    for (int j = 0; j < 8; j++) accS[j] = (f32x4){0.f, 0.f, 0.f, 0.f};
    __builtin_amdgcn_s_setprio(1);
#pragma unroll
    for (int hf = 0; hf < 2; hf++) {
#pragma unroll
      for (int ni = 0; ni < 4; ni++) {
        const int rk = ni * 16 + lm;
        bf16x8 b0 = *(const bf16x8*)&Ks[cur][hf][rk * 64 + ((quad ^ rb)) * 8];
        bf16x8 b1 = *(const bf16x8*)&Ks[cur][hf][rk * 64 + (((4 + quad) ^ rb)) * 8];
        f32x4 a = accS[hf * 4 + ni];
        a = __builtin_amdgcn_mfma_f32_16x16x32_bf16(aq0, b0, a, 0, 0, 0);
        a = __builtin_amdgcn_mfma_f32_16x16x32_bf16(aq1, b1, a, 0, 0, 0);
        accS[hf * 4 + ni] = a;
      }
    }
    __builtin_amdgcn_s_setprio(0);

    float mx[4];
#pragma unroll
    for (int r = 0; r < 4; r++) {
      float m0 = fmaxf(fmaxf(accS[0][r], accS[1][r]), fmaxf(accS[2][r], accS[3][r]));
      float m1 = fmaxf(fmaxf(accS[4][r], accS[5][r]), fmaxf(accS[6][r], accS[7][r]));
      float m8 = fmaxf(m0, m1);
      m8 = fmaxf(m8, __shfl_xor(m8, 1));
      m8 = fmaxf(m8, __shfl_xor(m8, 2));
      m8 = fmaxf(m8, __shfl_xor(m8, 4));
      m8 = fmaxf(m8, __shfl_xor(m8, 8));
      mx[r] = m8 * SC;
    }
    bool ok = (mx[0] - mrow[0] <= 8.0f) && (mx[1] - mrow[1] <= 8.0f) &&
              (mx[2] - mrow[2] <= 8.0f) && (mx[3] - mrow[3] <= 8.0f);
    if (!__all(ok)) {
#pragma unroll
      for (int r = 0; r < 4; r++) {
        float mnew = fmaxf(mrow[r], mx[r]);
        float al = exp2f(mrow[r] - mnew);
        mrow[r] = mnew;
        lsum[r] *= al;
#pragma unroll
        for (int di = 0; di < 4; di++) accO[di][r] *= al;
      }
    }
#pragma unroll
    for (int r = 0; r < 4; r++) {
      float sum = 0.f;
#pragma unroll
      for (int j = 0; j < 8; j++) {
        float p = exp2f(accS[j][r] * SC - mrow[r]);
        accS[j][r] = p;
        sum += p;
      }
      lsum[r] += sum;
    }

#pragma unroll
    for (int hf = 0; hf < 2; hf++) {
#pragma unroll
      for (int jj = 0; jj < 4; jj++)
#pragma unroll
        for (int r = 0; r < 4; r++) {
          int prow = quad * 4 + r;
          int c = jj * 16 + lm;
          Pw[prow * 64 + (((c >> 3) ^ (prow & 7)) << 3) + (c & 7)] =
              (__bf16)accS[hf * 4 + jj][r];
        }
      __builtin_amdgcn_s_setprio(1);
#pragma unroll
      for (int loc = 0; loc < 2; loc++) {
        bf16x8 ap = *(const bf16x8*)&Pw[lm * 64 + (((loc * 4 + quad) ^ rb)) * 8];
#pragma unroll
        for (int di = 0; di < 4; di++) {
          const int rv = di * 16 + lm;
          bf16x8 vv = *(const bf16x8*)&Vs[cur][hf]
              [rv * 64 + (((loc * 4 + quad) ^ rb)) * 8];
          accO[di] = __builtin_amdgcn_mfma_f32_16x16x32_bf16(ap, vv, accO[di], 0, 0, 0);
        }
      }
      __builtin_amdgcn_s_setprio(0);
    }
    __syncthreads();
  }

#pragma unroll
  for (int r = 0; r < 4; r++) {
    float sv = lsum[r];
    sv += __shfl_xor(sv, 1);
    sv += __shfl_xor(sv, 2);
    sv += __shfl_xor(sv, 4);
    sv += __shfl_xor(sv, 8);
    lsum[r] = sv;
  }

#pragma unroll
  for (int r = 0; r < 4; r++) {
    float inv = 1.0f / lsum[r];
    int prow = quad * 4 + r;
#pragma unroll
    for (int di = 0; di < 4; di++) {
      int col = di * 16 + lm;
      int cph = (col >> 3) ^ (prow & 7);
      Pw[prow * 64 + cph * 8 + (col & 7)] = (__bf16)(accO[di][r] * inv);
    }
  }
  bf16_t* abase = attn + (size_t)b * S_ * 1024 +
                  (size_t)(s0 + wave * 16) * 1024 + hh * 64;
#pragma unroll
  for (int it = 0; it < 2; it++) {
    int slot = it * 64 + lane;
    int orow = slot >> 3;
    int gc = slot & 7;
    int cph = gc ^ (orow & 7);
    bf16x8 val = *(const bf16x8*)&Pw[orow * 64 + cph * 8];
    *(bf16x8*)(abase + (size_t)orow * 1024 + gc * 8) = val;
  }
}

// ---------------- big-tile GEMM v10: 256x256 + counted-vmcnt streaming -------
// BM=256, BN=256, BK=64, 512 threads, 8 waves as 2M x 4N, per-wave 128x64
// (acc[8][4]). Geometry/addressing identical to verified v9. NEW: per K-tile
//   vmcnt(8)  [tile t ready; tile t+1's 8 loads stay in flight]
//   barrier
//   read all 24 frags of tile t into registers
//   lgkmcnt(0); sched_barrier; barrier   [buf[cur] dead for all waves]
//   STAGE8(t+2) into buf[cur]            [loads stream continuously]
//   64 MFMA
// -> the memory pipe never drains (v7/v6-proven counted-vmcnt pattern),
// fixing v9's 3 TB/s effective staged-BW limit. dbuf LDS = 128KB.
// M,N mult of 256; K mult of 64; grid blocks %8==0 (XCD-bijective swizzle).
// EPI: 0 = (+bias) -> bf16 ; 3 = gelu(acc+bias) -> bf16
template <int EPI>
__global__ __launch_bounds__(512) void gemm_bt_big(
    const bf16_t* __restrict__ A, int lda,
    const bf16_t* __restrict__ B, int ldb,
    bf16_t* __restrict__ C, int ldc,
    int M, int N, int K,
    const float* __restrict__ bias) {
  __shared__ __align__(16) bf16_t As[2][4][64 * 64];   // 64KB
  __shared__ __align__(16) bf16_t Bs[2][4][64 * 64];   // 64KB

  const int gx = gridDim.x;
  int d = blockIdx.x + gx * blockIdx.y;
  const int cpx = (gx * gridDim.y) >> 3;
  int wg = (d & 7) * cpx + (d >> 3);
  const int by = wg / gx;     // M-tile
  const int bx = wg % gx;     // N-tile

  const int t = threadIdx.x;
  const int wave = t >> 6;
  const int lane = t & 63;
  const int lm = lane & 15;
  const int quad = lane >> 4;
  const int wr = wave >> 2;   // 0..1: M half (128 rows)
  const int wc = wave & 3;    // 0..3: N quarter (64 cols)

  const int m0 = by * 256;
  const int n0 = bx * 256;

  f32x4 acc[8][4] = {};

  // staging: unit = 64 rows x 64 cols (8KB = 512 lanes x 16B);
  // thread t -> row t>>3, LDS slot t&7 holds global chunk (t&7)^(row&7)
  const int srow = t >> 3;
  const int scg = (t & 7) ^ (srow & 7);
  const int sod = t * 8;
  const bf16_t* Ag = A + (size_t)(m0 + srow) * lda + scg * 8;
  const bf16_t* Bg = B + (size_t)(n0 + srow) * ldb + scg * 8;
  const size_t aStep = (size_t)64 * lda;
  const size_t bStep = (size_t)64 * ldb;

#define STAGE8(buf, ko)                                        \
  async_copy16(Ag + (ko), &As[buf][0][sod]);                   \
  async_copy16(Ag + aStep + (ko), &As[buf][1][sod]);           \
  async_copy16(Ag + 2 * aStep + (ko), &As[buf][2][sod]);       \
  async_copy16(Ag + 3 * aStep + (ko), &As[buf][3][sod]);       \
  async_copy16(Bg + (ko), &Bs[buf][0][sod]);                   \
  async_copy16(Bg + bStep + (ko), &Bs[buf][1][sod]);           \
  async_copy16(Bg + 2 * bStep + (ko), &Bs[buf][2][sod]);       \
  async_copy16(Bg + 3 * bStep + (ko), &Bs[buf][3][sod]);

  const int niter = K >> 6;
  STAGE8(0, 0);
  STAGE8(1, 64);

  const int rbx = lm & 7;
  const int sl0 = (quad ^ rbx) * 8;          // ks=0 slot offset
  const int sl1 = ((4 + quad) ^ rbx) * 8;    // ks=1 slot offset
  const int abase = wr * 8192 + lm * 64;     // + (mi>>2)*4096 + (mi&3)*1024
  const int bbase = wc * 4096 + lm * 64;     // + ni*1024

  int cur = 0;
  for (int it = 0; it < niter; ++it) {
    // tile it ready; keep tile it+1's 8 loads in flight (never drain mid-loop)
    if (it + 1 < niter) {
      asm volatile("s_waitcnt vmcnt(8)" ::: "memory");
    } else {
      asm volatile("s_waitcnt vmcnt(0)" ::: "memory");
    }
    __builtin_amdgcn_s_barrier();

    const bf16_t* Ac = &As[cur][0][0];
    const bf16_t* Bc = &Bs[cur][0][0];

    // read ALL fragments of tile it into registers
    bf16x8 afr[8][2], bfr[4][2];
#pragma unroll
    for (int mi = 0; mi < 8; mi++) {
      const int aoff = abase + (mi >> 2) * 4096 + (mi & 3) * 1024;
      afr[mi][0] = *(const bf16x8*)&Ac[aoff + sl0];
      afr[mi][1] = *(const bf16x8*)&Ac[aoff + sl1];
    }
#pragma unroll
    for (int ni = 0; ni < 4; ni++) {
      bfr[ni][0] = *(const bf16x8*)&Bc[bbase + ni * 1024 + sl0];
      bfr[ni][1] = *(const bf16x8*)&Bc[bbase + ni * 1024 + sl1];
    }
    asm volatile("s_waitcnt lgkmcnt(0)" ::: "memory");
    __builtin_amdgcn_sched_barrier(0);
    __builtin_amdgcn_s_barrier();    // all waves done reading buf[cur]

    // stream next+1 tile into the buffer just freed
    if (it + 2 < niter) {
      const int ko = (it + 2) << 6;
      STAGE8(cur, ko);
    }

    __builtin_amdgcn_s_setprio(1);
#pragma unroll
    for (int mi = 0; mi < 8; mi++)
#pragma unroll
      for (int ni = 0; ni < 4; ni++) {
        acc[mi][ni] = __builtin_amdgcn_mfma_f32_16x16x32_bf16(
            afr[mi][0], bfr[ni][0], acc[mi][ni], 0, 0, 0);
        acc[mi][ni] = __builtin_amdgcn_mfma_f32_16x16x32_bf16(
            afr[mi][1], bfr[ni][1], acc[mi][ni], 0, 0, 0);
      }
    __builtin_amdgcn_s_setprio(0);
    cur ^= 1;
  }
#undef STAGE8

#pragma unroll
  for (int mi = 0; mi < 8; mi++) {
#pragma unroll
    for (int ni = 0; ni < 4; ni++) {
#pragma unroll
      for (int r = 0; r < 4; r++) {
        int row = m0 + wr * 128 + mi * 16 + quad * 4 + r;
        int col = n0 + wc * 64 + ni * 16 + lm;
        float v = acc[mi][ni][r];
        size_t idx = (size_t)row * ldc + col;
        if (EPI == 0) {
          if (bias) v += bias[col];
          C[idx] = (__bf16)v;
        } else if (EPI == 3) {
          v += bias[col];
          float u = 1.5957691216f * (v + 0.044715f * v * v * v);
          float g = v / (1.0f + __expf(-u));
          C[idx] = (__bf16)g;
        }
      }
    }
  }
}

// ---------------- C = A * B^T GEMM (v7, verified): 256x128, phase-split ------
// 512 threads, BM=256 BN=128 BK=64, 8 waves (4M x 2N), per-wave 64x64.
// Ring-of-3 LDS (144KB), staged 2 K-tiles ahead, counted vmcnt(6).
// Each K-tile split into 2 phases of 16 MFMA (double-barrier rhythm).
// EPI: 0 = (+bias) -> bf16 ; 1 = identity -> f32 ; 3 = gelu(acc+bias) -> bf16
template <int EPI>
__global__ __launch_bounds__(512) void gemm_bt(
    const bf16_t* __restrict__ A, int lda, long long sAz,
    const bf16_t* __restrict__ B, int ldb, long long sBz,
    void* __restrict__ Cv, int ldc, long long sCz,
    int M, int N, int K,
    const float* __restrict__ bias,
    float scale) {
  __shared__ __align__(16) bf16_t As[3][256 * 64];   // 96KB
  __shared__ __align__(16) bf16_t Bs[3][128 * 64];   // 48KB

  const int z = blockIdx.z;
  A += (size_t)z * sAz;
  B += (size_t)z * sBz;

  const int gx = gridDim.x;
  int d = blockIdx.x + gx * blockIdx.y;
  {
    const int cpx = (gx * gridDim.y) >> 3;
    int wg = (d & 7) * cpx + (d >> 3);
    const int by = wg / gx;     // M-tile
    const int bx = wg % gx;     // N-tile

    const int t = threadIdx.x;
    const int wave = t >> 6;
    const int lane = t & 63;
    const int lm = lane & 15;
    const int quad = lane >> 4;
    const int wr = wave >> 1;   // 0..3: M sub-block
    const int wc = wave & 1;    // 0..1: N sub-block

    const int m0 = by * 256;
    const int n0 = bx * 128;

    f32x4 acc[4][4] = {};

    const int srow = t >> 3;                    // 0..63
    const int scg = (t & 7) ^ (srow & 7);
    const int sod = t * 8;                      // LDS elem offset in unit
    const bf16_t* Ag = A + (size_t)(m0 + srow) * lda + scg * 8;
    const bf16_t* Bg = B + (size_t)(n0 + srow) * ldb + scg * 8;
    const size_t a64 = (size_t)64 * lda, a128 = (size_t)128 * lda,
                 a192 = (size_t)192 * lda, b64 = (size_t)64 * ldb;

#define STAGE6(buf, ko)                                      \
  async_copy16(Ag + (ko), &As[buf][sod]);                    \
  async_copy16(Ag + a64 + (ko), &As[buf][4096 + sod]);       \
  async_copy16(Ag + a128 + (ko), &As[buf][8192 + sod]);      \
  async_copy16(Ag + a192 + (ko), &As[buf][12288 + sod]);     \
  async_copy16(Bg + (ko), &Bs[buf][sod]);                    \
  async_copy16(Bg + b64 + (ko), &Bs[buf][4096 + sod]);

    const int niter = K >> 6;
    STAGE6(0, 0);
    STAGE6(1, 64);

    const int rbx = lm & 7;
    const int sl0 = (quad ^ rbx) * 8;          // ks=0 slot offset
    const int sl1 = ((4 + quad) ^ rbx) * 8;    // ks=1 slot offset
    const int arow = wr * 4096 + lm * 64;      // + mi*1024
    const int brow = wc * 4096 + lm * 64;

    int cur = 0;
    for (int it = 0; it < niter; ++it) {
      if (it + 1 < niter) {
        asm volatile("s_waitcnt vmcnt(6)" ::: "memory");
      } else {
        asm volatile("s_waitcnt vmcnt(0)" ::: "memory");
      }
      __builtin_amdgcn_s_barrier();            // buf[cur] ready for all waves
      const int nb = (cur >= 1) ? cur - 1 : 2; // ring slot for tile it+2
      const int ko = (it + 2) << 6;
      const bool st = (it + 2 < niter);

      // ---------------- phase A ----------------
      bf16x8 af0[2], af1[2], bfr[4][2];
      af0[0] = *(const bf16x8*)&As[cur][arow + sl0];
      af0[1] = *(const bf16x8*)&As[cur][arow + sl1];
      af1[0] = *(const bf16x8*)&As[cur][arow + 1024 + sl0];
      af1[1] = *(const bf16x8*)&As[cur][arow + 1024 + sl1];
#pragma unroll
      for (int i = 0; i < 4; i++) {
        bfr[i][0] = *(const bf16x8*)&Bs[cur][brow + i * 1024 + sl0];
        bfr[i][1] = *(const bf16x8*)&Bs[cur][brow + i * 1024 + sl1];
      }
      if (st) {
        async_copy16(Ag + ko, &As[nb][sod]);
        async_copy16(Ag + a64 + ko, &As[nb][4096 + sod]);
        async_copy16(Ag + a128 + ko, &As[nb][8192 + sod]);
      }
      __builtin_amdgcn_s_barrier();
      __builtin_amdgcn_s_setprio(1);
#pragma unroll
      for (int ks = 0; ks < 2; ks++)
#pragma unroll
        for (int ni = 0; ni < 4; ni++) {
          acc[0][ni] = __builtin_amdgcn_mfma_f32_16x16x32_bf16(
              af0[ks], bfr[ni][ks], acc[0][ni], 0, 0, 0);
          acc[1][ni] = __builtin_amdgcn_mfma_f32_16x16x32_bf16(
              af1[ks], bfr[ni][ks], acc[1][ni], 0, 0, 0);
        }
      __builtin_amdgcn_s_setprio(0);
      __builtin_amdgcn_s_barrier();

      // ---------------- phase B ----------------
      bf16x8 af2[2], af3[2];
      af2[0] = *(const bf16x8*)&As[cur][arow + 2048 + sl0];
      af2[1] = *(const bf16x8*)&As[cur][arow + 2048 + sl1];
      af3[0] = *(const bf16x8*)&As[cur][arow + 3072 + sl0];
      af3[1] = *(const bf16x8*)&As[cur][arow + 3072 + sl1];
      if (st) {
        async_copy16(Ag + a192 + ko, &As[nb][12288 + sod]);
        async_copy16(Bg + ko, &Bs[nb][sod]);
        async_copy16(Bg + b64 + ko, &Bs[nb][4096 + sod]);
      }
      __builtin_amdgcn_s_barrier();
      __builtin_amdgcn_s_setprio(1);
#pragma unroll
      for (int ks = 0; ks < 2; ks++)
#pragma unroll
        for (int ni = 0; ni < 4; ni++) {
          acc[2][ni] = __builtin_amdgcn_mfma_f32_16x16x32_bf16(
              af2[ks], bfr[ni][ks], acc[2][ni], 0, 0, 0);
          acc[3][ni] = __builtin_amdgcn_mfma_f32_16x16x32_bf16(
              af3[ks], bfr[ni][ks], acc[3][ni], 0, 0, 0);
        }
      __builtin_amdgcn_s_setprio(0);
      cur = (cur == 2) ? 0 : cur + 1;
    }
#undef STAGE6

    const size_t cz = (size_t)z * sCz;
#pragma unroll
    for (int mi = 0; mi < 4; mi++) {
#pragma unroll
      for (int ni = 0; ni < 4; ni++) {
#pragma unroll
        for (int r = 0; r < 4; r++) {
          int row = m0 + wr * 64 + mi * 16 + quad * 4 + r;
          int col = n0 + wc * 64 + ni * 16 + lm;
          float v = acc[mi][ni][r];
          size_t idx = cz + (size_t)row * ldc + col;
          if (EPI == 1) {
            ((float*)Cv)[idx] = v * scale;
          } else if (EPI == 0) {
            if (bias) v += bias[col];
            ((bf16_t*)Cv)[idx] = (__bf16)v;
          } else if (EPI == 3) {
            v += bias[col];
            float u = 1.5957691216f * (v + 0.044715f * v * v * v);
            float g = v / (1.0f + __expf(-u));
            ((bf16_t*)Cv)[idx] = (__bf16)g;
          }
        }
      }
    }
  }
}

// ---------------- Wo split-K reduce + residual + LN2 + modulate ----------------
__global__ __launch_bounds__(256) void reduce_ln(
    const float* __restrict__ part, const float* __restrict__ x,
    const float* __restrict__ bo, const float* __restrict__ mod,
    float* __restrict__ x1, bf16_t* __restrict__ h) {
  const int row = blockIdx.x;
  const int b = row >> 10;
  const int t = threadIdx.x;
  const int c = t * 4;
  const size_t idx = (size_t)row * 1024 + c;
  float4 p0 = *(const float4*)(part + idx);
  float4 p1 = *(const float4*)(part + 4194304 + idx);
  float4 bb = *(const float4*)(bo + c);
  float4 al = *(const float4*)(mod + (size_t)b * 6144 + 2048 + c);
  float4 xs = *(const float4*)(x + idx);
  float4 xv;
  xv.x = xs.x + al.x * (p0.x + p1.x + bb.x);
  xv.y = xs.y + al.y * (p0.y + p1.y + bb.y);
  xv.z = xs.z + al.z * (p0.z + p1.z + bb.z);
  xv.w = xs.w + al.w * (p0.w + p1.w + bb.w);
  *(float4*)(x1 + idx) = xv;

  float s = xv.x + xv.y + xv.z + xv.w;
  float q = xv.x*xv.x + xv.y*xv.y + xv.z*xv.z + xv.w*xv.w;
  const int wave = t >> 6, lane = t & 63;
#pragma unroll
  for (int offs = 32; offs; offs >>= 1) {
    s += __shfl_down(s, offs);
    q += __shfl_down(q, offs);
  }
  __shared__ float sb[4][2];
  if (lane == 0) { sb[wave][0] = s; sb[wave][1] = q; }
  __syncthreads();
  float st = sb[0][0] + sb[1][0] + sb[2][0] + sb[3][0];
  float qt = sb[0][1] + sb[1][1] + sb[2][1] + sb[3][1];
  float mu = st * (1.0f / D_);
  float var = qt * (1.0f / D_) - mu * mu;
  float rstd = rsqrtf(var + 1e-6f);
  const float* mb = mod + (size_t)b * 6144 + 3072;
  float4 gm = *(const float4*)(mb + c);
  float4 bt = *(const float4*)(mb + 1024 + c);
  bf16x4 pk;
  pk.x = (__bf16)((xv.x - mu) * rstd * (1.0f + bt.x) + gm.x);
  pk.y = (__bf16)((xv.y - mu) * rstd * (1.0f + bt.y) + gm.y);
  pk.z = (__bf16)((xv.z - mu) * rstd * (1.0f + bt.z) + gm.z);
  pk.w = (__bf16)((xv.w - mu) * rstd * (1.0f + bt.w) + gm.w);
  *(bf16x4*)(h + idx) = pk;
}

// ---------------- W2 split-K(2) reduction + epilogue ----------------
__global__ __launch_bounds__(256) void reduce_w2(
    const float* __restrict__ part, const float* __restrict__ x1,
    const float* __restrict__ b2, const float* __restrict__ mod,
    float* __restrict__ out) {
  const int idx = (blockIdx.x * 256 + threadIdx.x) * 4;
  const int col = idx & 1023;
  const int row = idx >> 10;
  const int b = row >> 10;
  float4 s0 = *(const float4*)(part + idx);
  float4 s1 = *(const float4*)(part + 4194304 + idx);
  float4 bb = *(const float4*)(b2 + col);
  float4 al = *(const float4*)(mod + (size_t)b * 6144 + 5120 + col);
  float4 rs = *(const float4*)(x1 + idx);
  float4 o;
  o.x = rs.x + al.x * (s0.x + s1.x + bb.x);
  o.y = rs.y + al.y * (s0.y + s1.y + bb.y);
  o.z = rs.z + al.z * (s0.z + s1.z + bb.z);
  o.w = rs.w + al.w * (s0.w + s1.w + bb.w);
  *(float4*)(out + idx) = o;
}

extern "C" void kernel_launch(void* const* d_in, const int* in_sizes, int n_in,
                              void* d_out, int out_size, void* d_ws, size_t ws_size,
                              hipStream_t stream) {
  (void)in_sizes; (void)n_in; (void)out_size; (void)ws_size;
  const float* x    = (const float*)d_in[0];
  const float* cond = (const float*)d_in[1];
  const float* Wq   = (const float*)d_in[2];
  const float* bq   = (const float*)d_in[3];
  const float* Wk   = (const float*)d_in[4];
  const float* bk   = (const float*)d_in[5];
  const float* Wv   = (const float*)d_in[6];
  const float* bv   = (const float*)d_in[7];
  const float* Wo   = (const float*)d_in[8];
  const float* bo   = (const float*)d_in[9];
  const float* W1   = (const float*)d_in[10];
  const float* b1   = (const float*)d_in[11];
  const float* W2   = (const float*)d_in[12];
  const float* b2   = (const float*)d_in[13];
  const float* Wada = (const float*)d_in[14];
  const float* bada = (const float*)d_in[15];

  uint8_t* ws = (uint8_t*)d_ws;
  bf16_t* wbf   = (bf16_t*)(ws + OFF_WBF);
  float*  bqkv  = (float*)(ws + OFF_BQKV);
  float*  mod   = (float*)(ws + OFF_MOD);
  bf16_t* h     = (bf16_t*)(ws + OFF_H);
  bf16_t* qkv   = (bf16_t*)(ws + OFF_QKV);
  bf16_t* vT    = (bf16_t*)(ws + OFF_VT);
  bf16_t* attn  = (bf16_t*)(ws + OFF_ATTN);
  float*  x1    = (float*)(ws + OFF_X1);
  float*  part  = (float*)(ws + OFF_PART);
  bf16_t* mlph  = (bf16_t*)(ws + OFF_MLPH);
  float* out = (float*)d_out;

  convert_pack<<<dim3(4096, 7, 1), 256, 0, stream>>>(Wq, Wk, Wv, Wo, W1, W2,
                                                     bq, bk, bv, wbf, bqkv);
  ada_mod<<<1536, 256, 0, stream>>>(cond, Wada, bada, mod);
  ln_modulate<<<4096, 256, 0, stream>>>(x, mod, h, 0);
  // qkv = h @ [Wq;Wk;Wv]^T + bias   (M=4096, N=3072, K=1024) grid 12x16=192
  gemm_bt_big<0><<<dim3(12, 16, 1), 512, 0, stream>>>(
      h, 1024, wbf, 1024, qkv, 3072, 4096, 3072, 1024, bqkv);
  transpose_v<<<dim3(16, 64, 1), 256, 0, stream>>>(qkv, vT);
  flash_attn<<<dim3(8, 64, 1), 512, 0, stream>>>(qkv, vT, attn);

  // Wo split-K=2: part[z] = attn[:, z*512:] @ Wo[:, z*512:]^T  grid 8x16x2
  gemm_bt<1><<<dim3(8, 16, 2), 512, 0, stream>>>(
      attn, 1024, 512, wbf + (size_t)3 * MEG, 1024, 512, part, 1024, 4194304,
      4096, 1024, 512, nullptr, 1.f);
  // x1 = x + alpha1*(sum part + bo); h = modulate(ln(x1), beta2, gama2)
  reduce_ln<<<4096, 256, 0, stream>>>(part, x, bo, mod, x1, h);

  // mlph = gelu(h @ W1^T + b1)   (M=4096, N=4096, K=1024) grid 16x16=256
  gemm_bt_big<3><<<dim3(16, 16, 1), 512, 0, stream>>>(
      h, 1024, wbf + (size_t)4 * MEG, 1024, mlph, 4096, 4096, 4096, 1024, b1);
  // W2 split-K=2  (M=4096, N=1024, K=2048 per z) grid 8x16x2
  gemm_bt<1><<<dim3(8, 16, 2), 512, 0, stream>>>(
      mlph, 4096, 2048, wbf + (size_t)8 * MEG, 4096, 2048, part, 1024, 4194304,
      4096, 1024, 2048, nullptr, 1.f);
  reduce_w2<<<4096, 256, 0, stream>>>(part, x1, b2, mod, out);
}